// Round 16
// baseline (128.283 us; speedup 1.0000x reference)
//
#include <hip/hip_runtime.h>

// Problem constants
#define NBOOKS 4
#define CODES  1024
#define DIM    64
#define NPOS   32768          // B*T*H*W
#define CCH    256            // NB*DIM (channel dim of z)
#define ENC_OFF  8388608
#define LOSS_OFF 8519680
#define PERP_OFF 8519681

// workspace byte offsets
#define WS_E2      0              // 4096 f32 (raw ||e||^2)
#define WS_EHI     16384          // 4096*64 f16 = 512 KB  (f16 of -2*e)
#define WS_IDX     1064960        // 131072 int
#define WS_CNT     1589248        // 4096 int
#define WS_PART    1605632        // 128 f32
#define WS_FLAGCNT 1607680        // 4 ints (per-book flag counts)
#define WS_FLAGS   1607696        // 4 x 32768 ints (per-book flag lists)

typedef _Float16 f16x8 __attribute__((ext_vector_type(8)));
typedef _Float16 f16x4 __attribute__((ext_vector_type(4)));
typedef float    f32x4 __attribute__((ext_vector_type(4)));

// ------------------------------------------- prep: e2, f16(-2e), zeroing
__global__ void k_eprep2(const float* __restrict__ emb, float* __restrict__ e2,
                         _Float16* __restrict__ ehi,
                         int* __restrict__ counts, int* __restrict__ flagcnt) {
    int i = blockIdx.x * 256 + threadIdx.x;            // row 0..4095 = k*1024+c
    counts[i] = 0;
    if (i < 4) flagcnt[i] = 0;
    const float4* e = (const float4*)(emb + ((size_t)i << 6));
    _Float16* hp = ehi + ((size_t)i << 6);
    float s = 0.f;
#pragma unroll
    for (int j = 0; j < 16; ++j) {
        float4 v = e[j];
        s += v.x * v.x + v.y * v.y + v.z * v.z + v.w * v.w;
        f16x4 hv;
        hv[0] = (_Float16)(-2.f * v.x);
        hv[1] = (_Float16)(-2.f * v.y);
        hv[2] = (_Float16)(-2.f * v.z);
        hv[3] = (_Float16)(-2.f * v.w);
        *(f16x4*)&hp[j * 4] = hv;
    }
    e2[i] = s;           // raw ||e||^2; score = e2 - 2x.e (sign handled in float domain)
}

// ---------------------------------------------------------------- MFMA argmin v10
// 1-TERM f16: score = e2 + mfma(f16(-2e), f16(x)); error std ~8e-3, margin
// 0.05 near-ties flagged (per-book lists) and exactly rescored in fp32.
// Block = 128 positions x all 1024 codes, one book; 4 waves x 32 pos each.
// E streamed in 32-code chunks (4 KB), 3-buffer LDS, 1 barrier/chunk,
// XOR-swizzled write+read; prefetch issued AFTER the barrier.
__global__ void __launch_bounds__(256, 4) k_argmin_mfma(
        const float* __restrict__ z, const float* __restrict__ e2g,
        const _Float16* __restrict__ ehi,
        int* __restrict__ idxbuf, int* __restrict__ flagcnt,
        int* __restrict__ flaglist) {
    __shared__ __attribute__((aligned(16))) char sE[3][4096];  // 32 codes x 128 B

    int tid = threadIdx.x;
    int wave = tid >> 6, lane = tid & 63;
    int lrow = lane >> 4, lcol = lane & 15;
    int k = blockIdx.y;
    int posbase = blockIdx.x * 128;
    int b = posbase >> 13, s0 = posbase & 8191;
    int wb = wave * 32;

    // ---- X fragments (f16 of z) straight into registers
    const float* zb = z + (((size_t)(b * CCH + k * DIM)) << 13) + s0 + wb;
    f16x8 Xh[2][2];
#pragma unroll
    for (int pt = 0; pt < 2; ++pt)
#pragma unroll
        for (int kc = 0; kc < 2; ++kc) {
            f16x8 hv;
#pragma unroll
            for (int e = 0; e < 8; ++e) {
                int d = kc * 32 + lrow * 8 + e;
                hv[e] = (_Float16)zb[((size_t)d << 13) + pt * 16 + lcol];
            }
            Xh[pt][kc] = hv;
        }

    // ---- E staging: 256 threads x 16 B = one 4 KB chunk (32 codes)
    int r = tid >> 3;                     // code row 0..31
    int q = tid & 7;                      // 16B column 0..7
    const char* bookh = (const char*)(ehi + ((size_t)k << 16));
    const char* src0 = bookh + r * 128 + q * 16;          // + chunk*4096
    int w0 = r * 128 + ((q ^ (r & 7)) << 4);

    const float* e2p = e2g + (k << 10) + lrow * 4;

    // prologue: stage chunk 0 into buffer 0; load chunk-0 e2 vectors
    *(f16x8*)&sE[0][w0] = *(const f16x8*)(src0);
    f32x4 ce2a = *(const f32x4*)(e2p);
    f32x4 ce2b = *(const f32x4*)(e2p + 16);

    float m1f[2][4], m2f[2][4];
#pragma unroll
    for (int pt = 0; pt < 2; ++pt)
#pragma unroll
        for (int rr = 0; rr < 4; ++rr) { m1f[pt][rr] = 3.4e38f; m2f[pt][rr] = 3.4e38f; }

    int sxk = (lcol & 7);
    int o0 = ((lrow ^ sxk) << 4);         // K-chunk 0 (dims 0..31)
    int o1 = (((4 + lrow) ^ sxk) << 4);   // K-chunk 1 (dims 32..63)
    int row0 = lcol << 7;                 // st=0 code row byte offset
    int row1 = (16 + lcol) << 7;          // st=1

    int cur = 0, nxt = 1, fre = 2;
    for (int it = 0; it < 32; ++it) {
        __syncthreads();                  // buffer cur ready; vmcnt already 0
        const char* sc = sE[cur];

        f16x8 eh0a = *(const f16x8*)(sc + row0 + o0);
        f16x8 eh1a = *(const f16x8*)(sc + row0 + o1);
        f16x8 eh0b = *(const f16x8*)(sc + row1 + o0);
        f16x8 eh1b = *(const f16x8*)(sc + row1 + o1);

        f16x8 nv0;
        f32x4 ne2a, ne2b;
        bool has = it < 31;
        if (has) {
            nv0 = *(const f16x8*)(src0 + (size_t)(it + 1) * 4096);
            ne2a = *(const f32x4*)(e2p + (it + 1) * 32);
            ne2b = *(const f32x4*)(e2p + (it + 1) * 32 + 16);
        }

#pragma unroll
        for (int st = 0; st < 2; ++st) {
            f16x8 eh0 = st ? eh0b : eh0a;
            f16x8 eh1 = st ? eh1b : eh1a;
            f32x4 e2v = st ? ce2b : ce2a;
            unsigned kit = (unsigned)(it * 2 + st);
#pragma unroll
            for (int pt = 0; pt < 2; ++pt) {
                f32x4 acc = e2v;          // score = ||e||^2 - 2x.e (1-term f16)
                acc = __builtin_amdgcn_mfma_f32_16x16x32_f16(eh0, Xh[pt][0], acc, 0, 0, 0);
                acc = __builtin_amdgcn_mfma_f32_16x16x32_f16(eh1, Xh[pt][1], acc, 0, 0, 0);
#pragma unroll
                for (int rr = 0; rr < 4; ++rr) {
                    float key = __uint_as_float(
                        (__float_as_uint(acc[rr]) & 0xFFFFFFC0u) | kit);
                    m2f[pt][rr] = __builtin_amdgcn_fmed3f(m1f[pt][rr], m2f[pt][rr], key);
                    m1f[pt][rr] = fminf(m1f[pt][rr], key);
                }
            }
        }

        if (has) {
            *(f16x8*)&sE[nxt][w0] = nv0;
            ce2a = ne2a; ce2b = ne2b;
        }
        int t = cur; cur = nxt; nxt = fre; fre = t;
    }

    // ---- within-thread merge over r slots (exact, index tie-break)
    float F1[2], F2[2]; int I1[2];
#pragma unroll
    for (int pt = 0; pt < 2; ++pt) {
        float f1 = 3.4e38f, f2 = 3.4e38f; int i1 = 0;
#pragma unroll
        for (int rr = 0; rr < 4; ++rr) {
            unsigned mb = __float_as_uint(m1f[pt][rr]);
            float f = __uint_as_float(mb & 0xFFFFFFC0u);
            int   c = (int)(mb & 63u) * 16 + lrow * 4 + rr;
            float g = __uint_as_float(__float_as_uint(m2f[pt][rr]) & 0xFFFFFFC0u);
            bool take = (f < f1) || (f == f1 && c < i1);
            float loser = take ? f1 : f;
            f2 = fminf(fminf(f2, g), loser);
            if (take) { f1 = f; i1 = c; }
        }
        F1[pt] = f1; F2[pt] = f2; I1[pt] = i1;
    }

    // ---- merge across lrow groups (4 lanes hold same position)
#pragma unroll
    for (int off = 16; off < 64; off <<= 1) {
#pragma unroll
        for (int pt = 0; pt < 2; ++pt) {
            float om1 = __shfl_xor(F1[pt], off);
            float om2 = __shfl_xor(F2[pt], off);
            int   oi  = __shfl_xor(I1[pt], off);
            bool take = (om1 < F1[pt]) || (om1 == F1[pt] && oi < I1[pt]);
            float loser = take ? F1[pt] : om1;
            F2[pt] = fminf(fminf(F2[pt], om2), loser);
            if (take) { F1[pt] = om1; I1[pt] = oi; }
        }
    }

    // ---- write idx, flag near-ties into per-book list
    if (lane < 16) {
#pragma unroll
        for (int pt = 0; pt < 2; ++pt) {
            int n = posbase + wb + pt * 16 + lane;
            idxbuf[(k << 15) + n] = I1[pt];
            float thr = fmaf(fabsf(F1[pt]), 3.2e-5f, 5.0e-2f);
            if (F2[pt] - F1[pt] < thr) {
                int slot = atomicAdd(&flagcnt[k], 1);
                flaglist[(k << 15) + slot] = n;
            }
        }
    }
}

// ---------------------------------------------------------------- rescore v6
// Batched: 8 same-book flags per block share ONE codebook pass (L2 traffic /8).
// Thread owns 4 codes. j-loop NOT unrolled (unroll 1): 4 loads + 256 FMA per
// iteration, loop-carried state = 32 accums -> no register spill (v5 hit 256
// VGPR + 4.8 MB scratch traffic from full-unroll load hoisting).
__global__ void __launch_bounds__(256) k_rescore(
        const float* __restrict__ z, const float* __restrict__ emb,
        const float* __restrict__ e2g, const int* __restrict__ flagcnt,
        const int* __restrict__ flaglist, int* __restrict__ idxbuf) {
    __shared__ __attribute__((aligned(16))) float xsh[8][64];
    __shared__ int meta[8];
    __shared__ float bm[8][256];
    __shared__ int   bx[8][256];
    int tid = threadIdx.x;
    int wave = tid >> 6, lane = tid & 63;
    int k = blockIdx.y;
    int nf = flagcnt[k];
    const f32x4* ek4 = (const f32x4*)(emb + ((size_t)k << 16));
    const float* ee  = e2g + (k << 10);

    for (int base = blockIdx.x * 8; base < nf; base += gridDim.x * 8) {
        __syncthreads();                   // reuse guard
        if (tid < 8) meta[tid] = (base + tid < nf) ? flaglist[(k << 15) + base + tid] : -1;
        __syncthreads();
        for (int j = tid; j < 512; j += 256) {
            int p = j >> 6, d = j & 63;
            int n = meta[p];
            if (n >= 0) {
                int bb = n >> 13, s = n & 8191;
                xsh[p][d] = z[(((size_t)(bb * CCH + k * DIM + d)) << 13) + s];
            }
        }
        __syncthreads();

        // 4 codes x 8 flags: 32 loop-carried accumulators
        const f32x4* ev0 = ek4 + (size_t)(tid) * 16;
        const f32x4* ev1 = ek4 + (size_t)(256 + tid) * 16;
        const f32x4* ev2 = ek4 + (size_t)(512 + tid) * 16;
        const f32x4* ev3 = ek4 + (size_t)(768 + tid) * 16;
        float a0[8], a1[8], a2[8], a3[8];
#pragma unroll
        for (int f = 0; f < 8; ++f) { a0[f] = 0.f; a1[f] = 0.f; a2[f] = 0.f; a3[f] = 0.f; }
#pragma unroll 1
        for (int j = 0; j < 16; ++j) {
            f32x4 q0 = ev0[j], q1 = ev1[j], q2 = ev2[j], q3 = ev3[j];
#pragma unroll
            for (int f = 0; f < 8; ++f) {
                f32x4 xv = *(const f32x4*)&xsh[f][j * 4];   // lane-uniform: broadcast
                a0[f] = fmaf(xv[0], q0[0], a0[f]); a0[f] = fmaf(xv[1], q0[1], a0[f]);
                a0[f] = fmaf(xv[2], q0[2], a0[f]); a0[f] = fmaf(xv[3], q0[3], a0[f]);
                a1[f] = fmaf(xv[0], q1[0], a1[f]); a1[f] = fmaf(xv[1], q1[1], a1[f]);
                a1[f] = fmaf(xv[2], q1[2], a1[f]); a1[f] = fmaf(xv[3], q1[3], a1[f]);
                a2[f] = fmaf(xv[0], q2[0], a2[f]); a2[f] = fmaf(xv[1], q2[1], a2[f]);
                a2[f] = fmaf(xv[2], q2[2], a2[f]); a2[f] = fmaf(xv[3], q2[3], a2[f]);
                a3[f] = fmaf(xv[0], q3[0], a3[f]); a3[f] = fmaf(xv[1], q3[1], a3[f]);
                a3[f] = fmaf(xv[2], q3[2], a3[f]); a3[f] = fmaf(xv[3], q3[3], a3[f]);
            }
        }
        float e0 = ee[tid], e1 = ee[256 + tid], e2 = ee[512 + tid], e3 = ee[768 + tid];
#pragma unroll
        for (int f = 0; f < 8; ++f) {
            float best = fmaf(-2.f, a0[f], e0); int bi = tid;
            float d1 = fmaf(-2.f, a1[f], e1);
            float d2 = fmaf(-2.f, a2[f], e2);
            float d3 = fmaf(-2.f, a3[f], e3);
            if (d1 < best) { best = d1; bi = 256 + tid; }
            if (d2 < best) { best = d2; bi = 512 + tid; }
            if (d3 < best) { best = d3; bi = 768 + tid; }
            bm[f][tid] = best;
            bx[f][tid] = bi;
        }
        __syncthreads();

        // wave w reduces flags w and w+4 (256 values each)
#pragma unroll
        for (int ff = 0; ff < 2; ++ff) {
            int f = wave + ff * 4;
            float bv = bm[f][lane]; int bi = bx[f][lane];
#pragma unroll
            for (int o = 64; o < 256; o += 64) {
                float v2 = bm[f][lane + o]; int x2 = bx[f][lane + o];
                if (v2 < bv || (v2 == bv && x2 < bi)) { bv = v2; bi = x2; }
            }
#pragma unroll
            for (int off = 1; off < 64; off <<= 1) {
                float ob = __shfl_xor(bv, off);
                int   oi = __shfl_xor(bi, off);
                if (ob < bv || (ob == bv && oi < bi)) { bv = ob; bi = oi; }
            }
            if (lane == 0 && meta[f] >= 0) idxbuf[(k << 15) + meta[f]] = bi;
        }
    }
}

// ---------------------------------------------------------------- gather+loss
// 4 consecutive positions per thread -> float4 z loads / q stores.
__global__ void __launch_bounds__(256) k_quant(
        const float* __restrict__ z, const float* __restrict__ emb,
        const int* __restrict__ idxbuf, float* __restrict__ out,
        int* __restrict__ counts, float* __restrict__ partial) {
    int tid = threadIdx.x;
    int q = blockIdx.x * 256 + tid;       // quad index
    int n0 = q * 4;
    int k = blockIdx.y;
    int b = n0 >> 13;
    int s = n0 & 8191;

    int4 bi = *(const int4*)&idxbuf[(k << 15) + n0];
    const f32x4* e0 = (const f32x4*)(emb + ((size_t)k << 16) + ((size_t)bi.x << 6));
    const f32x4* e1 = (const f32x4*)(emb + ((size_t)k << 16) + ((size_t)bi.y << 6));
    const f32x4* e2 = (const f32x4*)(emb + ((size_t)k << 16) + ((size_t)bi.z << 6));
    const f32x4* e3 = (const f32x4*)(emb + ((size_t)k << 16) + ((size_t)bi.w << 6));
    size_t base = (((size_t)(b * CCH + k * DIM)) << 13) + s;

    float sq = 0.f;
#pragma unroll
    for (int j = 0; j < 16; ++j) {
        f32x4 q0 = e0[j], q1 = e1[j], q2 = e2[j], q3 = e3[j];
#pragma unroll
        for (int i = 0; i < 4; ++i) {
            int d = j * 4 + i;
            f32x4 zv = *(const f32x4*)(z + base + ((size_t)d << 13));
            f32x4 ov = {q0[i], q1[i], q2[i], q3[i]};
            *(f32x4*)(out + base + ((size_t)d << 13)) = ov;
            f32x4 df = zv - ov;
            sq = fmaf(df[0], df[0], sq);
            sq = fmaf(df[1], df[1], sq);
            sq = fmaf(df[2], df[2], sq);
            sq = fmaf(df[3], df[3], sq);
        }
    }

    out[ENC_OFF + (size_t)(n0 + 0) * NBOOKS + k] = (float)bi.x;
    out[ENC_OFF + (size_t)(n0 + 1) * NBOOKS + k] = (float)bi.y;
    out[ENC_OFF + (size_t)(n0 + 2) * NBOOKS + k] = (float)bi.z;
    out[ENC_OFF + (size_t)(n0 + 3) * NBOOKS + k] = (float)bi.w;
    atomicAdd(&counts[(k << 10) + bi.x], 1);
    atomicAdd(&counts[(k << 10) + bi.y], 1);
    atomicAdd(&counts[(k << 10) + bi.z], 1);
    atomicAdd(&counts[(k << 10) + bi.w], 1);

    for (int off = 32; off; off >>= 1) sq += __shfl_down(sq, off, 64);
    __shared__ float red[4];
    if ((tid & 63) == 0) red[tid >> 6] = sq;
    __syncthreads();
    if (tid == 0)
        partial[blockIdx.y * gridDim.x + blockIdx.x] = (red[0] + red[1]) + (red[2] + red[3]);
}

// ---------------------------------------------------------------- finalize v2
__global__ void __launch_bounds__(256) k_fin(
        const int* __restrict__ counts, const float* __restrict__ partial,
        float* __restrict__ out) {
    __shared__ float shl[4];
    __shared__ float shp[4];
    int tid = threadIdx.x;
    int wave = tid >> 6, lane = tid & 63;

    // loss: 128 partials (32 blocks x 4 books)
    float s = tid < 128 ? partial[tid] : 0.f;
    for (int off = 32; off; off >>= 1) s += __shfl_down(s, off, 64);
    if (lane == 0) shl[wave] = s;

    // perplexity: wave w handles book w, lane handles 16 codes
    float h = 0.f;
    const int* ck = counts + (wave << 10) + lane * 16;
#pragma unroll
    for (int j = 0; j < 16; ++j) {
        float p = (float)ck[j] * (1.f / 32768.f);
        h += p * logf(p + 1e-10f);
    }
    for (int off = 32; off; off >>= 1) h += __shfl_down(h, off, 64);
    if (lane == 0) shp[wave] = expf(-h);
    __syncthreads();
    if (tid == 0) {
        out[LOSS_OFF] = 0.25f * ((shl[0] + shl[1]) + (shl[2] + shl[3])) / 8388608.f;
        out[PERP_OFF] = 0.25f * ((shp[0] + shp[1]) + (shp[2] + shp[3]));
    }
}

// ----------------------------------------------------------------
extern "C" void kernel_launch(void* const* d_in, const int* in_sizes, int n_in,
                              void* d_out, int out_size, void* d_ws, size_t ws_size,
                              hipStream_t stream) {
    const float* z   = (const float*)d_in[0];
    const float* emb = (const float*)d_in[1];
    float* out = (float*)d_out;
    char* ws = (char*)d_ws;

    float*    e2       = (float*)(ws + WS_E2);
    _Float16* ehi      = (_Float16*)(ws + WS_EHI);
    int*      idxbuf   = (int*)(ws + WS_IDX);
    int*      counts   = (int*)(ws + WS_CNT);
    float*    partial  = (float*)(ws + WS_PART);
    int*      flagcnt  = (int*)(ws + WS_FLAGCNT);
    int*      flaglist = (int*)(ws + WS_FLAGS);

    k_eprep2<<<16, 256, 0, stream>>>(emb, e2, ehi, counts, flagcnt);

    dim3 agrid(NPOS / 128, NBOOKS);
    k_argmin_mfma<<<agrid, 256, 0, stream>>>(z, e2, ehi, idxbuf, flagcnt, flaglist);

    dim3 rgrid(256, NBOOKS);
    k_rescore<<<rgrid, 256, 0, stream>>>(z, emb, e2, flagcnt, flaglist, idxbuf);

    dim3 qgrid(NPOS / 1024, NBOOKS);
    k_quant<<<qgrid, 256, 0, stream>>>(z, emb, idxbuf, out, counts, partial);
    k_fin<<<1, 256, 0, stream>>>(counts, partial, out);
}

// Round 18
// 119.756 us; speedup vs baseline: 1.0712x; 1.0712x over previous
//
#include <hip/hip_runtime.h>

// Problem constants
#define NBOOKS 4
#define CODES  1024
#define DIM    64
#define NPOS   32768          // B*T*H*W
#define CCH    256            // NB*DIM (channel dim of z)
#define ENC_OFF  8388608
#define LOSS_OFF 8519680
#define PERP_OFF 8519681

// workspace byte offsets
#define WS_E2      0              // 4096 f32 (raw ||e||^2)
#define WS_EHI     16384          // 4096*64 f16 = 512 KB  (f16 of -2*e)
#define WS_IDX     1064960        // 131072 int
#define WS_CNT     1589248        // 4096 int
#define WS_PART    1605632        // 128 f32
#define WS_FLAGCNT 1607680        // 4 ints (per-book flag counts)
#define WS_FLAGS   1607696        // 4 x 32768 ints (per-book flag lists)

typedef _Float16 f16x8 __attribute__((ext_vector_type(8)));
typedef _Float16 f16x4 __attribute__((ext_vector_type(4)));
typedef float    f32x4 __attribute__((ext_vector_type(4)));

// ------------------------------------------- prep: e2, f16(-2e), zeroing
__global__ void k_eprep2(const float* __restrict__ emb, float* __restrict__ e2,
                         _Float16* __restrict__ ehi,
                         int* __restrict__ counts, int* __restrict__ flagcnt) {
    int i = blockIdx.x * 256 + threadIdx.x;            // row 0..4095 = k*1024+c
    counts[i] = 0;
    if (i < 4) flagcnt[i] = 0;
    const float4* e = (const float4*)(emb + ((size_t)i << 6));
    _Float16* hp = ehi + ((size_t)i << 6);
    float s = 0.f;
#pragma unroll
    for (int j = 0; j < 16; ++j) {
        float4 v = e[j];
        s += v.x * v.x + v.y * v.y + v.z * v.z + v.w * v.w;
        f16x4 hv;
        hv[0] = (_Float16)(-2.f * v.x);
        hv[1] = (_Float16)(-2.f * v.y);
        hv[2] = (_Float16)(-2.f * v.z);
        hv[3] = (_Float16)(-2.f * v.w);
        *(f16x4*)&hp[j * 4] = hv;
    }
    e2[i] = s;           // raw ||e||^2; score = e2 - 2x.e (sign handled in float domain)
}

// ---------------------------------------------------------------- MFMA argmin v10
// (UNCHANGED from round 16 — passed rounds 14/15/16.)
// 1-TERM f16: score = e2 + mfma(f16(-2e), f16(x)); margin 0.05 near-ties
// flagged (per-book lists) and exactly rescored in fp32.
// Block = 128 positions x all 1024 codes, one book; 4 waves x 32 pos each.
// E streamed in 32-code chunks (4 KB), 3-buffer LDS, 1 barrier/chunk,
// XOR-swizzled write+read; prefetch issued AFTER the barrier.
__global__ void __launch_bounds__(256, 4) k_argmin_mfma(
        const float* __restrict__ z, const float* __restrict__ e2g,
        const _Float16* __restrict__ ehi,
        int* __restrict__ idxbuf, int* __restrict__ flagcnt,
        int* __restrict__ flaglist) {
    __shared__ __attribute__((aligned(16))) char sE[3][4096];  // 32 codes x 128 B

    int tid = threadIdx.x;
    int wave = tid >> 6, lane = tid & 63;
    int lrow = lane >> 4, lcol = lane & 15;
    int k = blockIdx.y;
    int posbase = blockIdx.x * 128;
    int b = posbase >> 13, s0 = posbase & 8191;
    int wb = wave * 32;

    // ---- X fragments (f16 of z) straight into registers
    const float* zb = z + (((size_t)(b * CCH + k * DIM)) << 13) + s0 + wb;
    f16x8 Xh[2][2];
#pragma unroll
    for (int pt = 0; pt < 2; ++pt)
#pragma unroll
        for (int kc = 0; kc < 2; ++kc) {
            f16x8 hv;
#pragma unroll
            for (int e = 0; e < 8; ++e) {
                int d = kc * 32 + lrow * 8 + e;
                hv[e] = (_Float16)zb[((size_t)d << 13) + pt * 16 + lcol];
            }
            Xh[pt][kc] = hv;
        }

    // ---- E staging: 256 threads x 16 B = one 4 KB chunk (32 codes)
    int r = tid >> 3;                     // code row 0..31
    int q = tid & 7;                      // 16B column 0..7
    const char* bookh = (const char*)(ehi + ((size_t)k << 16));
    const char* src0 = bookh + r * 128 + q * 16;          // + chunk*4096
    int w0 = r * 128 + ((q ^ (r & 7)) << 4);

    const float* e2p = e2g + (k << 10) + lrow * 4;

    // prologue: stage chunk 0 into buffer 0; load chunk-0 e2 vectors
    *(f16x8*)&sE[0][w0] = *(const f16x8*)(src0);
    f32x4 ce2a = *(const f32x4*)(e2p);
    f32x4 ce2b = *(const f32x4*)(e2p + 16);

    float m1f[2][4], m2f[2][4];
#pragma unroll
    for (int pt = 0; pt < 2; ++pt)
#pragma unroll
        for (int rr = 0; rr < 4; ++rr) { m1f[pt][rr] = 3.4e38f; m2f[pt][rr] = 3.4e38f; }

    int sxk = (lcol & 7);
    int o0 = ((lrow ^ sxk) << 4);         // K-chunk 0 (dims 0..31)
    int o1 = (((4 + lrow) ^ sxk) << 4);   // K-chunk 1 (dims 32..63)
    int row0 = lcol << 7;                 // st=0 code row byte offset
    int row1 = (16 + lcol) << 7;          // st=1

    int cur = 0, nxt = 1, fre = 2;
    for (int it = 0; it < 32; ++it) {
        __syncthreads();                  // buffer cur ready; vmcnt already 0
        const char* sc = sE[cur];

        f16x8 eh0a = *(const f16x8*)(sc + row0 + o0);
        f16x8 eh1a = *(const f16x8*)(sc + row0 + o1);
        f16x8 eh0b = *(const f16x8*)(sc + row1 + o0);
        f16x8 eh1b = *(const f16x8*)(sc + row1 + o1);

        f16x8 nv0;
        f32x4 ne2a, ne2b;
        bool has = it < 31;
        if (has) {
            nv0 = *(const f16x8*)(src0 + (size_t)(it + 1) * 4096);
            ne2a = *(const f32x4*)(e2p + (it + 1) * 32);
            ne2b = *(const f32x4*)(e2p + (it + 1) * 32 + 16);
        }

#pragma unroll
        for (int st = 0; st < 2; ++st) {
            f16x8 eh0 = st ? eh0b : eh0a;
            f16x8 eh1 = st ? eh1b : eh1a;
            f32x4 e2v = st ? ce2b : ce2a;
            unsigned kit = (unsigned)(it * 2 + st);
#pragma unroll
            for (int pt = 0; pt < 2; ++pt) {
                f32x4 acc = e2v;          // score = ||e||^2 - 2x.e (1-term f16)
                acc = __builtin_amdgcn_mfma_f32_16x16x32_f16(eh0, Xh[pt][0], acc, 0, 0, 0);
                acc = __builtin_amdgcn_mfma_f32_16x16x32_f16(eh1, Xh[pt][1], acc, 0, 0, 0);
#pragma unroll
                for (int rr = 0; rr < 4; ++rr) {
                    float key = __uint_as_float(
                        (__float_as_uint(acc[rr]) & 0xFFFFFFC0u) | kit);
                    m2f[pt][rr] = __builtin_amdgcn_fmed3f(m1f[pt][rr], m2f[pt][rr], key);
                    m1f[pt][rr] = fminf(m1f[pt][rr], key);
                }
            }
        }

        if (has) {
            *(f16x8*)&sE[nxt][w0] = nv0;
            ce2a = ne2a; ce2b = ne2b;
        }
        int t = cur; cur = nxt; nxt = fre; fre = t;
    }

    // ---- within-thread merge over r slots (exact, index tie-break)
    float F1[2], F2[2]; int I1[2];
#pragma unroll
    for (int pt = 0; pt < 2; ++pt) {
        float f1 = 3.4e38f, f2 = 3.4e38f; int i1 = 0;
#pragma unroll
        for (int rr = 0; rr < 4; ++rr) {
            unsigned mb = __float_as_uint(m1f[pt][rr]);
            float f = __uint_as_float(mb & 0xFFFFFFC0u);
            int   c = (int)(mb & 63u) * 16 + lrow * 4 + rr;
            float g = __uint_as_float(__float_as_uint(m2f[pt][rr]) & 0xFFFFFFC0u);
            bool take = (f < f1) || (f == f1 && c < i1);
            float loser = take ? f1 : f;
            f2 = fminf(fminf(f2, g), loser);
            if (take) { f1 = f; i1 = c; }
        }
        F1[pt] = f1; F2[pt] = f2; I1[pt] = i1;
    }

    // ---- merge across lrow groups (4 lanes hold same position)
#pragma unroll
    for (int off = 16; off < 64; off <<= 1) {
#pragma unroll
        for (int pt = 0; pt < 2; ++pt) {
            float om1 = __shfl_xor(F1[pt], off);
            float om2 = __shfl_xor(F2[pt], off);
            int   oi  = __shfl_xor(I1[pt], off);
            bool take = (om1 < F1[pt]) || (om1 == F1[pt] && oi < I1[pt]);
            float loser = take ? F1[pt] : om1;
            F2[pt] = fminf(fminf(F2[pt], om2), loser);
            if (take) { F1[pt] = om1; I1[pt] = oi; }
        }
    }

    // ---- write idx, flag near-ties into per-book list (margin 0.05, proven)
    if (lane < 16) {
#pragma unroll
        for (int pt = 0; pt < 2; ++pt) {
            int n = posbase + wb + pt * 16 + lane;
            idxbuf[(k << 15) + n] = I1[pt];
            float thr = fmaf(fabsf(F1[pt]), 3.2e-5f, 5.0e-2f);
            if (F2[pt] - F1[pt] < thr) {
                int slot = atomicAdd(&flagcnt[k], 1);
                flaglist[(k << 15) + slot] = n;
            }
        }
    }
}

// ---------------------------------------------------------------- rescore v7
// Batched (8 same-book flags per block, one codebook pass) + software-
// pipelined E loads: iteration j issues j+1's 4 rows before j's 256 FMAs,
// hiding L2 latency; unroll 1 keeps loop-carried state ~140 VGPR (no spill;
// v5's full unroll hoisted 64 loads -> 256 VGPR + scratch, v6's bare
// unroll-1 serialized loads).
__global__ void __launch_bounds__(256) k_rescore(
        const float* __restrict__ z, const float* __restrict__ emb,
        const float* __restrict__ e2g, const int* __restrict__ flagcnt,
        const int* __restrict__ flaglist, int* __restrict__ idxbuf) {
    __shared__ __attribute__((aligned(16))) float xsh[8][64];
    __shared__ int meta[8];
    __shared__ float bm[8][256];
    __shared__ int   bx[8][256];
    int tid = threadIdx.x;
    int wave = tid >> 6, lane = tid & 63;
    int k = blockIdx.y;
    int nf = flagcnt[k];
    const f32x4* ek4 = (const f32x4*)(emb + ((size_t)k << 16));
    const float* ee  = e2g + (k << 10);

    for (int base = blockIdx.x * 8; base < nf; base += gridDim.x * 8) {
        __syncthreads();                   // reuse guard
        if (tid < 8) meta[tid] = (base + tid < nf) ? flaglist[(k << 15) + base + tid] : -1;
        __syncthreads();
        for (int j = tid; j < 512; j += 256) {
            int p = j >> 6, d = j & 63;
            int n = meta[p];
            if (n >= 0) {
                int bb = n >> 13, s = n & 8191;
                xsh[p][d] = z[(((size_t)(bb * CCH + k * DIM + d)) << 13) + s];
            }
        }
        __syncthreads();

        // 4 codes x 8 flags: 32 loop-carried accumulators; 1-deep load pipe
        const f32x4* ev0 = ek4 + (size_t)(tid) * 16;
        const f32x4* ev1 = ek4 + (size_t)(256 + tid) * 16;
        const f32x4* ev2 = ek4 + (size_t)(512 + tid) * 16;
        const f32x4* ev3 = ek4 + (size_t)(768 + tid) * 16;
        float a0[8], a1[8], a2[8], a3[8];
#pragma unroll
        for (int f = 0; f < 8; ++f) { a0[f] = 0.f; a1[f] = 0.f; a2[f] = 0.f; a3[f] = 0.f; }
        f32x4 q0 = ev0[0], q1 = ev1[0], q2 = ev2[0], q3 = ev3[0];
#pragma unroll 1
        for (int j = 0; j < 16; ++j) {
            f32x4 p0 = q0, p1 = q1, p2 = q2, p3 = q3;
            if (j < 15) {                  // issue next rows; consumed next iter
                q0 = ev0[j + 1]; q1 = ev1[j + 1];
                q2 = ev2[j + 1]; q3 = ev3[j + 1];
            }
#pragma unroll
            for (int f = 0; f < 8; ++f) {
                f32x4 xv = *(const f32x4*)&xsh[f][j * 4];   // lane-uniform: broadcast
                a0[f] = fmaf(xv[0], p0[0], a0[f]); a0[f] = fmaf(xv[1], p0[1], a0[f]);
                a0[f] = fmaf(xv[2], p0[2], a0[f]); a0[f] = fmaf(xv[3], p0[3], a0[f]);
                a1[f] = fmaf(xv[0], p1[0], a1[f]); a1[f] = fmaf(xv[1], p1[1], a1[f]);
                a1[f] = fmaf(xv[2], p1[2], a1[f]); a1[f] = fmaf(xv[3], p1[3], a1[f]);
                a2[f] = fmaf(xv[0], p2[0], a2[f]); a2[f] = fmaf(xv[1], p2[1], a2[f]);
                a2[f] = fmaf(xv[2], p2[2], a2[f]); a2[f] = fmaf(xv[3], p2[3], a2[f]);
                a3[f] = fmaf(xv[0], p3[0], a3[f]); a3[f] = fmaf(xv[1], p3[1], a3[f]);
                a3[f] = fmaf(xv[2], p3[2], a3[f]); a3[f] = fmaf(xv[3], p3[3], a3[f]);
            }
        }
        float e0 = ee[tid], e1 = ee[256 + tid], e2 = ee[512 + tid], e3 = ee[768 + tid];
#pragma unroll
        for (int f = 0; f < 8; ++f) {
            float best = fmaf(-2.f, a0[f], e0); int bi = tid;
            float d1 = fmaf(-2.f, a1[f], e1);
            float d2 = fmaf(-2.f, a2[f], e2);
            float d3 = fmaf(-2.f, a3[f], e3);
            if (d1 < best) { best = d1; bi = 256 + tid; }
            if (d2 < best) { best = d2; bi = 512 + tid; }
            if (d3 < best) { best = d3; bi = 768 + tid; }
            bm[f][tid] = best;
            bx[f][tid] = bi;
        }
        __syncthreads();

        // wave w reduces flags w and w+4 (256 values each)
#pragma unroll
        for (int ff = 0; ff < 2; ++ff) {
            int f = wave + ff * 4;
            float bv = bm[f][lane]; int bi = bx[f][lane];
#pragma unroll
            for (int o = 64; o < 256; o += 64) {
                float v2 = bm[f][lane + o]; int x2 = bx[f][lane + o];
                if (v2 < bv || (v2 == bv && x2 < bi)) { bv = v2; bi = x2; }
            }
#pragma unroll
            for (int off = 1; off < 64; off <<= 1) {
                float ob = __shfl_xor(bv, off);
                int   oi = __shfl_xor(bi, off);
                if (ob < bv || (ob == bv && oi < bi)) { bv = ob; bi = oi; }
            }
            if (lane == 0 && meta[f] >= 0) idxbuf[(k << 15) + meta[f]] = bi;
        }
    }
}

// ---------------------------------------------------------------- gather+loss
// 4 consecutive positions per thread -> float4 z loads / q stores.
__global__ void __launch_bounds__(256) k_quant(
        const float* __restrict__ z, const float* __restrict__ emb,
        const int* __restrict__ idxbuf, float* __restrict__ out,
        int* __restrict__ counts, float* __restrict__ partial) {
    int tid = threadIdx.x;
    int q = blockIdx.x * 256 + tid;       // quad index
    int n0 = q * 4;
    int k = blockIdx.y;
    int b = n0 >> 13;
    int s = n0 & 8191;

    int4 bi = *(const int4*)&idxbuf[(k << 15) + n0];
    const f32x4* e0 = (const f32x4*)(emb + ((size_t)k << 16) + ((size_t)bi.x << 6));
    const f32x4* e1 = (const f32x4*)(emb + ((size_t)k << 16) + ((size_t)bi.y << 6));
    const f32x4* e2 = (const f32x4*)(emb + ((size_t)k << 16) + ((size_t)bi.z << 6));
    const f32x4* e3 = (const f32x4*)(emb + ((size_t)k << 16) + ((size_t)bi.w << 6));
    size_t base = (((size_t)(b * CCH + k * DIM)) << 13) + s;

    float sq = 0.f;
#pragma unroll
    for (int j = 0; j < 16; ++j) {
        f32x4 q0 = e0[j], q1 = e1[j], q2 = e2[j], q3 = e3[j];
#pragma unroll
        for (int i = 0; i < 4; ++i) {
            int d = j * 4 + i;
            f32x4 zv = *(const f32x4*)(z + base + ((size_t)d << 13));
            f32x4 ov = {q0[i], q1[i], q2[i], q3[i]};
            *(f32x4*)(out + base + ((size_t)d << 13)) = ov;
            f32x4 df = zv - ov;
            sq = fmaf(df[0], df[0], sq);
            sq = fmaf(df[1], df[1], sq);
            sq = fmaf(df[2], df[2], sq);
            sq = fmaf(df[3], df[3], sq);
        }
    }

    out[ENC_OFF + (size_t)(n0 + 0) * NBOOKS + k] = (float)bi.x;
    out[ENC_OFF + (size_t)(n0 + 1) * NBOOKS + k] = (float)bi.y;
    out[ENC_OFF + (size_t)(n0 + 2) * NBOOKS + k] = (float)bi.z;
    out[ENC_OFF + (size_t)(n0 + 3) * NBOOKS + k] = (float)bi.w;
    atomicAdd(&counts[(k << 10) + bi.x], 1);
    atomicAdd(&counts[(k << 10) + bi.y], 1);
    atomicAdd(&counts[(k << 10) + bi.z], 1);
    atomicAdd(&counts[(k << 10) + bi.w], 1);

    for (int off = 32; off; off >>= 1) sq += __shfl_down(sq, off, 64);
    __shared__ float red[4];
    if ((tid & 63) == 0) red[tid >> 6] = sq;
    __syncthreads();
    if (tid == 0)
        partial[blockIdx.y * gridDim.x + blockIdx.x] = (red[0] + red[1]) + (red[2] + red[3]);
}

// ---------------------------------------------------------------- finalize v2
__global__ void __launch_bounds__(256) k_fin(
        const int* __restrict__ counts, const float* __restrict__ partial,
        float* __restrict__ out) {
    __shared__ float shl[4];
    __shared__ float shp[4];
    int tid = threadIdx.x;
    int wave = tid >> 6, lane = tid & 63;

    // loss: 128 partials (32 blocks x 4 books)
    float s = tid < 128 ? partial[tid] : 0.f;
    for (int off = 32; off; off >>= 1) s += __shfl_down(s, off, 64);
    if (lane == 0) shl[wave] = s;

    // perplexity: wave w handles book w, lane handles 16 codes
    float h = 0.f;
    const int* ck = counts + (wave << 10) + lane * 16;
#pragma unroll
    for (int j = 0; j < 16; ++j) {
        float p = (float)ck[j] * (1.f / 32768.f);
        h += p * logf(p + 1e-10f);
    }
    for (int off = 32; off; off >>= 1) h += __shfl_down(h, off, 64);
    if (lane == 0) shp[wave] = expf(-h);
    __syncthreads();
    if (tid == 0) {
        out[LOSS_OFF] = 0.25f * ((shl[0] + shl[1]) + (shl[2] + shl[3])) / 8388608.f;
        out[PERP_OFF] = 0.25f * ((shp[0] + shp[1]) + (shp[2] + shp[3]));
    }
}

// ----------------------------------------------------------------
extern "C" void kernel_launch(void* const* d_in, const int* in_sizes, int n_in,
                              void* d_out, int out_size, void* d_ws, size_t ws_size,
                              hipStream_t stream) {
    const float* z   = (const float*)d_in[0];
    const float* emb = (const float*)d_in[1];
    float* out = (float*)d_out;
    char* ws = (char*)d_ws;

    float*    e2       = (float*)(ws + WS_E2);
    _Float16* ehi      = (_Float16*)(ws + WS_EHI);
    int*      idxbuf   = (int*)(ws + WS_IDX);
    int*      counts   = (int*)(ws + WS_CNT);
    float*    partial  = (float*)(ws + WS_PART);
    int*      flagcnt  = (int*)(ws + WS_FLAGCNT);
    int*      flaglist = (int*)(ws + WS_FLAGS);

    k_eprep2<<<16, 256, 0, stream>>>(emb, e2, ehi, counts, flagcnt);

    dim3 agrid(NPOS / 128, NBOOKS);
    k_argmin_mfma<<<agrid, 256, 0, stream>>>(z, e2, ehi, idxbuf, flagcnt, flaglist);

    dim3 rgrid(256, NBOOKS);
    k_rescore<<<rgrid, 256, 0, stream>>>(z, emb, e2, flagcnt, flaglist, idxbuf);

    dim3 qgrid(NPOS / 1024, NBOOKS);
    k_quant<<<qgrid, 256, 0, stream>>>(z, emb, idxbuf, out, counts, partial);
    k_fin<<<1, 256, 0, stream>>>(counts, partial, out);
}

// Round 19
// 109.375 us; speedup vs baseline: 1.1729x; 1.0949x over previous
//
#include <hip/hip_runtime.h>

// Problem constants
#define NBOOKS 4
#define CODES  1024
#define DIM    64
#define NPOS   32768          // B*T*H*W
#define CCH    256            // NB*DIM (channel dim of z)
#define ENC_OFF  8388608
#define LOSS_OFF 8519680
#define PERP_OFF 8519681

// workspace byte offsets
#define WS_E2      0              // 4096 f32 (raw ||e||^2)
#define WS_EHI     16384          // 4096*64 f16 = 512 KB  (f16 of -2*e)
#define WS_IDX     1064960        // 131072 int
#define WS_CNT     1589248        // 4096 int
#define WS_PART    1605632        // 128 f32
#define WS_FLAGCNT 1607680        // 4 ints (per-book flag counts)
#define WS_FLAGS   1607696        // 4 x 32768 ints (per-book flag lists)

typedef _Float16 f16x8 __attribute__((ext_vector_type(8)));
typedef _Float16 f16x4 __attribute__((ext_vector_type(4)));
typedef float    f32x4 __attribute__((ext_vector_type(4)));

// ------------------------------------------- prep: e2, f16(-2e), zeroing
__global__ void k_eprep2(const float* __restrict__ emb, float* __restrict__ e2,
                         _Float16* __restrict__ ehi,
                         int* __restrict__ counts, int* __restrict__ flagcnt) {
    int i = blockIdx.x * 256 + threadIdx.x;            // row 0..4095 = k*1024+c
    counts[i] = 0;
    if (i < 4) flagcnt[i] = 0;
    const float4* e = (const float4*)(emb + ((size_t)i << 6));
    _Float16* hp = ehi + ((size_t)i << 6);
    float s = 0.f;
#pragma unroll
    for (int j = 0; j < 16; ++j) {
        float4 v = e[j];
        s += v.x * v.x + v.y * v.y + v.z * v.z + v.w * v.w;
        f16x4 hv;
        hv[0] = (_Float16)(-2.f * v.x);
        hv[1] = (_Float16)(-2.f * v.y);
        hv[2] = (_Float16)(-2.f * v.z);
        hv[3] = (_Float16)(-2.f * v.w);
        *(f16x4*)&hp[j * 4] = hv;
    }
    e2[i] = s;           // raw ||e||^2; score = e2 - 2x.e (sign handled in float domain)
}

// ---------------------------------------------------------------- MFMA argmin v10
// (UNCHANGED — passed rounds 14/15/16/18.)
// 1-TERM f16: score = e2 + mfma(f16(-2e), f16(x)); margin 0.05 near-ties
// flagged (per-book lists) and exactly rescored in fp32.
// Block = 128 positions x all 1024 codes, one book; 4 waves x 32 pos each.
// E streamed in 32-code chunks (4 KB), 3-buffer LDS, 1 barrier/chunk,
// XOR-swizzled write+read; prefetch issued AFTER the barrier.
__global__ void __launch_bounds__(256, 4) k_argmin_mfma(
        const float* __restrict__ z, const float* __restrict__ e2g,
        const _Float16* __restrict__ ehi,
        int* __restrict__ idxbuf, int* __restrict__ flagcnt,
        int* __restrict__ flaglist) {
    __shared__ __attribute__((aligned(16))) char sE[3][4096];  // 32 codes x 128 B

    int tid = threadIdx.x;
    int wave = tid >> 6, lane = tid & 63;
    int lrow = lane >> 4, lcol = lane & 15;
    int k = blockIdx.y;
    int posbase = blockIdx.x * 128;
    int b = posbase >> 13, s0 = posbase & 8191;
    int wb = wave * 32;

    // ---- X fragments (f16 of z) straight into registers
    const float* zb = z + (((size_t)(b * CCH + k * DIM)) << 13) + s0 + wb;
    f16x8 Xh[2][2];
#pragma unroll
    for (int pt = 0; pt < 2; ++pt)
#pragma unroll
        for (int kc = 0; kc < 2; ++kc) {
            f16x8 hv;
#pragma unroll
            for (int e = 0; e < 8; ++e) {
                int d = kc * 32 + lrow * 8 + e;
                hv[e] = (_Float16)zb[((size_t)d << 13) + pt * 16 + lcol];
            }
            Xh[pt][kc] = hv;
        }

    // ---- E staging: 256 threads x 16 B = one 4 KB chunk (32 codes)
    int r = tid >> 3;                     // code row 0..31
    int q = tid & 7;                      // 16B column 0..7
    const char* bookh = (const char*)(ehi + ((size_t)k << 16));
    const char* src0 = bookh + r * 128 + q * 16;          // + chunk*4096
    int w0 = r * 128 + ((q ^ (r & 7)) << 4);

    const float* e2p = e2g + (k << 10) + lrow * 4;

    // prologue: stage chunk 0 into buffer 0; load chunk-0 e2 vectors
    *(f16x8*)&sE[0][w0] = *(const f16x8*)(src0);
    f32x4 ce2a = *(const f32x4*)(e2p);
    f32x4 ce2b = *(const f32x4*)(e2p + 16);

    float m1f[2][4], m2f[2][4];
#pragma unroll
    for (int pt = 0; pt < 2; ++pt)
#pragma unroll
        for (int rr = 0; rr < 4; ++rr) { m1f[pt][rr] = 3.4e38f; m2f[pt][rr] = 3.4e38f; }

    int sxk = (lcol & 7);
    int o0 = ((lrow ^ sxk) << 4);         // K-chunk 0 (dims 0..31)
    int o1 = (((4 + lrow) ^ sxk) << 4);   // K-chunk 1 (dims 32..63)
    int row0 = lcol << 7;                 // st=0 code row byte offset
    int row1 = (16 + lcol) << 7;          // st=1

    int cur = 0, nxt = 1, fre = 2;
    for (int it = 0; it < 32; ++it) {
        __syncthreads();                  // buffer cur ready; vmcnt already 0
        const char* sc = sE[cur];

        f16x8 eh0a = *(const f16x8*)(sc + row0 + o0);
        f16x8 eh1a = *(const f16x8*)(sc + row0 + o1);
        f16x8 eh0b = *(const f16x8*)(sc + row1 + o0);
        f16x8 eh1b = *(const f16x8*)(sc + row1 + o1);

        f16x8 nv0;
        f32x4 ne2a, ne2b;
        bool has = it < 31;
        if (has) {
            nv0 = *(const f16x8*)(src0 + (size_t)(it + 1) * 4096);
            ne2a = *(const f32x4*)(e2p + (it + 1) * 32);
            ne2b = *(const f32x4*)(e2p + (it + 1) * 32 + 16);
        }

#pragma unroll
        for (int st = 0; st < 2; ++st) {
            f16x8 eh0 = st ? eh0b : eh0a;
            f16x8 eh1 = st ? eh1b : eh1a;
            f32x4 e2v = st ? ce2b : ce2a;
            unsigned kit = (unsigned)(it * 2 + st);
#pragma unroll
            for (int pt = 0; pt < 2; ++pt) {
                f32x4 acc = e2v;          // score = ||e||^2 - 2x.e (1-term f16)
                acc = __builtin_amdgcn_mfma_f32_16x16x32_f16(eh0, Xh[pt][0], acc, 0, 0, 0);
                acc = __builtin_amdgcn_mfma_f32_16x16x32_f16(eh1, Xh[pt][1], acc, 0, 0, 0);
#pragma unroll
                for (int rr = 0; rr < 4; ++rr) {
                    float key = __uint_as_float(
                        (__float_as_uint(acc[rr]) & 0xFFFFFFC0u) | kit);
                    m2f[pt][rr] = __builtin_amdgcn_fmed3f(m1f[pt][rr], m2f[pt][rr], key);
                    m1f[pt][rr] = fminf(m1f[pt][rr], key);
                }
            }
        }

        if (has) {
            *(f16x8*)&sE[nxt][w0] = nv0;
            ce2a = ne2a; ce2b = ne2b;
        }
        int t = cur; cur = nxt; nxt = fre; fre = t;
    }

    // ---- within-thread merge over r slots (exact, index tie-break)
    float F1[2], F2[2]; int I1[2];
#pragma unroll
    for (int pt = 0; pt < 2; ++pt) {
        float f1 = 3.4e38f, f2 = 3.4e38f; int i1 = 0;
#pragma unroll
        for (int rr = 0; rr < 4; ++rr) {
            unsigned mb = __float_as_uint(m1f[pt][rr]);
            float f = __uint_as_float(mb & 0xFFFFFFC0u);
            int   c = (int)(mb & 63u) * 16 + lrow * 4 + rr;
            float g = __uint_as_float(__float_as_uint(m2f[pt][rr]) & 0xFFFFFFC0u);
            bool take = (f < f1) || (f == f1 && c < i1);
            float loser = take ? f1 : f;
            f2 = fminf(fminf(f2, g), loser);
            if (take) { f1 = f; i1 = c; }
        }
        F1[pt] = f1; F2[pt] = f2; I1[pt] = i1;
    }

    // ---- merge across lrow groups (4 lanes hold same position)
#pragma unroll
    for (int off = 16; off < 64; off <<= 1) {
#pragma unroll
        for (int pt = 0; pt < 2; ++pt) {
            float om1 = __shfl_xor(F1[pt], off);
            float om2 = __shfl_xor(F2[pt], off);
            int   oi  = __shfl_xor(I1[pt], off);
            bool take = (om1 < F1[pt]) || (om1 == F1[pt] && oi < I1[pt]);
            float loser = take ? F1[pt] : om1;
            F2[pt] = fminf(fminf(F2[pt], om2), loser);
            if (take) { F1[pt] = om1; I1[pt] = oi; }
        }
    }

    // ---- write idx, flag near-ties into per-book list (margin 0.05, proven)
    if (lane < 16) {
#pragma unroll
        for (int pt = 0; pt < 2; ++pt) {
            int n = posbase + wb + pt * 16 + lane;
            idxbuf[(k << 15) + n] = I1[pt];
            float thr = fmaf(fabsf(F1[pt]), 3.2e-5f, 5.0e-2f);
            if (F2[pt] - F1[pt] < thr) {
                int slot = atomicAdd(&flagcnt[k], 1);
                flaglist[(k << 15) + slot] = n;
            }
        }
    }
}

// ---------------------------------------------------------------- rescore v8
// Batched (8 same-book flags per block, one codebook pass) + 2-DEEP pair
// pipeline: generations A(j),B(j+1) in regs while C(j+2),D(j+3) are in
// flight; 256 FMAs (~512 cyc) cover the ~500 cyc L2 latency. Loop-carried
// state ~130 VGPR: no spill (v5), no exposure (v7's 1-deep 256-cyc cover).
__global__ void __launch_bounds__(256) k_rescore(
        const float* __restrict__ z, const float* __restrict__ emb,
        const float* __restrict__ e2g, const int* __restrict__ flagcnt,
        const int* __restrict__ flaglist, int* __restrict__ idxbuf) {
    __shared__ __attribute__((aligned(16))) float xsh[8][64];
    __shared__ int meta[8];
    __shared__ float bm[8][256];
    __shared__ int   bx[8][256];
    int tid = threadIdx.x;
    int wave = tid >> 6, lane = tid & 63;
    int k = blockIdx.y;
    int nf = flagcnt[k];
    const f32x4* ek4 = (const f32x4*)(emb + ((size_t)k << 16));
    const float* ee  = e2g + (k << 10);

    for (int base = blockIdx.x * 8; base < nf; base += gridDim.x * 8) {
        __syncthreads();                   // reuse guard
        if (tid < 8) meta[tid] = (base + tid < nf) ? flaglist[(k << 15) + base + tid] : -1;
        __syncthreads();
        for (int j = tid; j < 512; j += 256) {
            int p = j >> 6, d = j & 63;
            int n = meta[p];
            if (n >= 0) {
                int bb = n >> 13, s = n & 8191;
                xsh[p][d] = z[(((size_t)(bb * CCH + k * DIM + d)) << 13) + s];
            }
        }
        __syncthreads();

        const f32x4* ev0 = ek4 + (size_t)(tid) * 16;
        const f32x4* ev1 = ek4 + (size_t)(256 + tid) * 16;
        const f32x4* ev2 = ek4 + (size_t)(512 + tid) * 16;
        const f32x4* ev3 = ek4 + (size_t)(768 + tid) * 16;
        float a0[8], a1[8], a2[8], a3[8];
#pragma unroll
        for (int f = 0; f < 8; ++f) { a0[f] = 0.f; a1[f] = 0.f; a2[f] = 0.f; a3[f] = 0.f; }

        // preload generations A(j=0), B(j=1)
        f32x4 A0 = ev0[0], A1 = ev1[0], A2 = ev2[0], A3 = ev3[0];
        f32x4 B0 = ev0[1], B1 = ev1[1], B2 = ev2[1], B3 = ev3[1];
#pragma unroll 1
        for (int jj = 0; jj < 8; ++jj) {
            int j = jj * 2;
            // issue next pair (j+2, j+3) before this pair's 256 FMAs
            f32x4 C0, C1, C2, C3, D0, D1, D2, D3;
            bool has = jj < 7;
            if (has) {
                C0 = ev0[j + 2]; C1 = ev1[j + 2]; C2 = ev2[j + 2]; C3 = ev3[j + 2];
                D0 = ev0[j + 3]; D1 = ev1[j + 3]; D2 = ev2[j + 3]; D3 = ev3[j + 3];
            }
#pragma unroll
            for (int f = 0; f < 8; ++f) {
                f32x4 xa = *(const f32x4*)&xsh[f][j * 4];       // lane-uniform
                f32x4 xb = *(const f32x4*)&xsh[f][j * 4 + 4];
                a0[f] = fmaf(xa[0], A0[0], a0[f]); a0[f] = fmaf(xa[1], A0[1], a0[f]);
                a0[f] = fmaf(xa[2], A0[2], a0[f]); a0[f] = fmaf(xa[3], A0[3], a0[f]);
                a1[f] = fmaf(xa[0], A1[0], a1[f]); a1[f] = fmaf(xa[1], A1[1], a1[f]);
                a1[f] = fmaf(xa[2], A1[2], a1[f]); a1[f] = fmaf(xa[3], A1[3], a1[f]);
                a2[f] = fmaf(xa[0], A2[0], a2[f]); a2[f] = fmaf(xa[1], A2[1], a2[f]);
                a2[f] = fmaf(xa[2], A2[2], a2[f]); a2[f] = fmaf(xa[3], A2[3], a2[f]);
                a3[f] = fmaf(xa[0], A3[0], a3[f]); a3[f] = fmaf(xa[1], A3[1], a3[f]);
                a3[f] = fmaf(xa[2], A3[2], a3[f]); a3[f] = fmaf(xa[3], A3[3], a3[f]);
                a0[f] = fmaf(xb[0], B0[0], a0[f]); a0[f] = fmaf(xb[1], B0[1], a0[f]);
                a0[f] = fmaf(xb[2], B0[2], a0[f]); a0[f] = fmaf(xb[3], B0[3], a0[f]);
                a1[f] = fmaf(xb[0], B1[0], a1[f]); a1[f] = fmaf(xb[1], B1[1], a1[f]);
                a1[f] = fmaf(xb[2], B1[2], a1[f]); a1[f] = fmaf(xb[3], B1[3], a1[f]);
                a2[f] = fmaf(xb[0], B2[0], a2[f]); a2[f] = fmaf(xb[1], B2[1], a2[f]);
                a2[f] = fmaf(xb[2], B2[2], a2[f]); a2[f] = fmaf(xb[3], B2[3], a2[f]);
                a3[f] = fmaf(xb[0], B3[0], a3[f]); a3[f] = fmaf(xb[1], B3[1], a3[f]);
                a3[f] = fmaf(xb[2], B3[2], a3[f]); a3[f] = fmaf(xb[3], B3[3], a3[f]);
            }
            if (has) {
                A0 = C0; A1 = C1; A2 = C2; A3 = C3;
                B0 = D0; B1 = D1; B2 = D2; B3 = D3;
            }
        }
        float e0 = ee[tid], e1 = ee[256 + tid], e2 = ee[512 + tid], e3 = ee[768 + tid];
#pragma unroll
        for (int f = 0; f < 8; ++f) {
            float best = fmaf(-2.f, a0[f], e0); int bi = tid;
            float d1 = fmaf(-2.f, a1[f], e1);
            float d2 = fmaf(-2.f, a2[f], e2);
            float d3 = fmaf(-2.f, a3[f], e3);
            if (d1 < best) { best = d1; bi = 256 + tid; }
            if (d2 < best) { best = d2; bi = 512 + tid; }
            if (d3 < best) { best = d3; bi = 768 + tid; }
            bm[f][tid] = best;
            bx[f][tid] = bi;
        }
        __syncthreads();

        // wave w reduces flags w and w+4 (256 values each)
#pragma unroll
        for (int ff = 0; ff < 2; ++ff) {
            int f = wave + ff * 4;
            float bv = bm[f][lane]; int bi = bx[f][lane];
#pragma unroll
            for (int o = 64; o < 256; o += 64) {
                float v2 = bm[f][lane + o]; int x2 = bx[f][lane + o];
                if (v2 < bv || (v2 == bv && x2 < bi)) { bv = v2; bi = x2; }
            }
#pragma unroll
            for (int off = 1; off < 64; off <<= 1) {
                float ob = __shfl_xor(bv, off);
                int   oi = __shfl_xor(bi, off);
                if (ob < bv || (ob == bv && oi < bi)) { bv = ob; bi = oi; }
            }
            if (lane == 0 && meta[f] >= 0) idxbuf[(k << 15) + meta[f]] = bi;
        }
    }
}

// ---------------------------------------------------------------- gather+loss
// 4 consecutive positions per thread -> float4 z loads / q stores.
__global__ void __launch_bounds__(256) k_quant(
        const float* __restrict__ z, const float* __restrict__ emb,
        const int* __restrict__ idxbuf, float* __restrict__ out,
        int* __restrict__ counts, float* __restrict__ partial) {
    int tid = threadIdx.x;
    int q = blockIdx.x * 256 + tid;       // quad index
    int n0 = q * 4;
    int k = blockIdx.y;
    int b = n0 >> 13;
    int s = n0 & 8191;

    int4 bi = *(const int4*)&idxbuf[(k << 15) + n0];
    const f32x4* e0 = (const f32x4*)(emb + ((size_t)k << 16) + ((size_t)bi.x << 6));
    const f32x4* e1 = (const f32x4*)(emb + ((size_t)k << 16) + ((size_t)bi.y << 6));
    const f32x4* e2 = (const f32x4*)(emb + ((size_t)k << 16) + ((size_t)bi.z << 6));
    const f32x4* e3 = (const f32x4*)(emb + ((size_t)k << 16) + ((size_t)bi.w << 6));
    size_t base = (((size_t)(b * CCH + k * DIM)) << 13) + s;

    float sq = 0.f;
#pragma unroll
    for (int j = 0; j < 16; ++j) {
        f32x4 q0 = e0[j], q1 = e1[j], q2 = e2[j], q3 = e3[j];
#pragma unroll
        for (int i = 0; i < 4; ++i) {
            int d = j * 4 + i;
            f32x4 zv = *(const f32x4*)(z + base + ((size_t)d << 13));
            f32x4 ov = {q0[i], q1[i], q2[i], q3[i]};
            *(f32x4*)(out + base + ((size_t)d << 13)) = ov;
            f32x4 df = zv - ov;
            sq = fmaf(df[0], df[0], sq);
            sq = fmaf(df[1], df[1], sq);
            sq = fmaf(df[2], df[2], sq);
            sq = fmaf(df[3], df[3], sq);
        }
    }

    out[ENC_OFF + (size_t)(n0 + 0) * NBOOKS + k] = (float)bi.x;
    out[ENC_OFF + (size_t)(n0 + 1) * NBOOKS + k] = (float)bi.y;
    out[ENC_OFF + (size_t)(n0 + 2) * NBOOKS + k] = (float)bi.z;
    out[ENC_OFF + (size_t)(n0 + 3) * NBOOKS + k] = (float)bi.w;
    atomicAdd(&counts[(k << 10) + bi.x], 1);
    atomicAdd(&counts[(k << 10) + bi.y], 1);
    atomicAdd(&counts[(k << 10) + bi.z], 1);
    atomicAdd(&counts[(k << 10) + bi.w], 1);

    for (int off = 32; off; off >>= 1) sq += __shfl_down(sq, off, 64);
    __shared__ float red[4];
    if ((tid & 63) == 0) red[tid >> 6] = sq;
    __syncthreads();
    if (tid == 0)
        partial[blockIdx.y * gridDim.x + blockIdx.x] = (red[0] + red[1]) + (red[2] + red[3]);
}

// ---------------------------------------------------------------- finalize v2
__global__ void __launch_bounds__(256) k_fin(
        const int* __restrict__ counts, const float* __restrict__ partial,
        float* __restrict__ out) {
    __shared__ float shl[4];
    __shared__ float shp[4];
    int tid = threadIdx.x;
    int wave = tid >> 6, lane = tid & 63;

    // loss: 128 partials (32 blocks x 4 books)
    float s = tid < 128 ? partial[tid] : 0.f;
    for (int off = 32; off; off >>= 1) s += __shfl_down(s, off, 64);
    if (lane == 0) shl[wave] = s;

    // perplexity: wave w handles book w, lane handles 16 codes
    float h = 0.f;
    const int* ck = counts + (wave << 10) + lane * 16;
#pragma unroll
    for (int j = 0; j < 16; ++j) {
        float p = (float)ck[j] * (1.f / 32768.f);
        h += p * logf(p + 1e-10f);
    }
    for (int off = 32; off; off >>= 1) h += __shfl_down(h, off, 64);
    if (lane == 0) shp[wave] = expf(-h);
    __syncthreads();
    if (tid == 0) {
        out[LOSS_OFF] = 0.25f * ((shl[0] + shl[1]) + (shl[2] + shl[3])) / 8388608.f;
        out[PERP_OFF] = 0.25f * ((shp[0] + shp[1]) + (shp[2] + shp[3]));
    }
}

// ----------------------------------------------------------------
extern "C" void kernel_launch(void* const* d_in, const int* in_sizes, int n_in,
                              void* d_out, int out_size, void* d_ws, size_t ws_size,
                              hipStream_t stream) {
    const float* z   = (const float*)d_in[0];
    const float* emb = (const float*)d_in[1];
    float* out = (float*)d_out;
    char* ws = (char*)d_ws;

    float*    e2       = (float*)(ws + WS_E2);
    _Float16* ehi      = (_Float16*)(ws + WS_EHI);
    int*      idxbuf   = (int*)(ws + WS_IDX);
    int*      counts   = (int*)(ws + WS_CNT);
    float*    partial  = (float*)(ws + WS_PART);
    int*      flagcnt  = (int*)(ws + WS_FLAGCNT);
    int*      flaglist = (int*)(ws + WS_FLAGS);

    k_eprep2<<<16, 256, 0, stream>>>(emb, e2, ehi, counts, flagcnt);

    dim3 agrid(NPOS / 128, NBOOKS);
    k_argmin_mfma<<<agrid, 256, 0, stream>>>(z, e2, ehi, idxbuf, flagcnt, flaglist);

    dim3 rgrid(256, NBOOKS);
    k_rescore<<<rgrid, 256, 0, stream>>>(z, emb, e2, flagcnt, flaglist, idxbuf);

    dim3 qgrid(NPOS / 1024, NBOOKS);
    k_quant<<<qgrid, 256, 0, stream>>>(z, emb, idxbuf, out, counts, partial);
    k_fin<<<1, 256, 0, stream>>>(counts, partial, out);
}

// Round 20
// 107.233 us; speedup vs baseline: 1.1963x; 1.0200x over previous
//
#include <hip/hip_runtime.h>

// Problem constants
#define NBOOKS 4
#define CODES  1024
#define DIM    64
#define NPOS   32768          // B*T*H*W
#define CCH    256            // NB*DIM (channel dim of z)
#define ENC_OFF  8388608
#define LOSS_OFF 8519680
#define PERP_OFF 8519681

// workspace byte offsets
#define WS_E2      0              // 4096 f32 (raw ||e||^2)
#define WS_EHI     16384          // 4096*64 f16 = 512 KB  (f16 of -2*e)
#define WS_IDX     1064960        // 131072 int
#define WS_CNT     1589248        // 4096 int
#define WS_PART    1605632        // 128 f32
#define WS_FLAGCNT 1607680        // 4 ints (per-book flag counts)
#define WS_FLAGS   1607696        // 4 x 32768 ints (per-book flag lists)

typedef _Float16 f16x8 __attribute__((ext_vector_type(8)));
typedef _Float16 f16x4 __attribute__((ext_vector_type(4)));
typedef float    f32x4 __attribute__((ext_vector_type(4)));

// ------------------------------------------- prep: e2, f16(-2e), zeroing
__global__ void k_eprep2(const float* __restrict__ emb, float* __restrict__ e2,
                         _Float16* __restrict__ ehi,
                         int* __restrict__ counts, int* __restrict__ flagcnt) {
    int i = blockIdx.x * 256 + threadIdx.x;            // row 0..4095 = k*1024+c
    counts[i] = 0;
    if (i < 4) flagcnt[i] = 0;
    const float4* e = (const float4*)(emb + ((size_t)i << 6));
    _Float16* hp = ehi + ((size_t)i << 6);
    float s = 0.f;
#pragma unroll
    for (int j = 0; j < 16; ++j) {
        float4 v = e[j];
        s += v.x * v.x + v.y * v.y + v.z * v.z + v.w * v.w;
        f16x4 hv;
        hv[0] = (_Float16)(-2.f * v.x);
        hv[1] = (_Float16)(-2.f * v.y);
        hv[2] = (_Float16)(-2.f * v.z);
        hv[3] = (_Float16)(-2.f * v.w);
        *(f16x4*)&hp[j * 4] = hv;
    }
    e2[i] = s;           // raw ||e||^2; score = e2 - 2x.e (sign handled in float domain)
}

// ---------------------------------------------------------------- MFMA argmin v12
// Same numerics as the proven v10 (1-term f16, margin 0.05, per-book flags),
// but block = 64 positions (1 pt per wave) -> grid 2048 = 8 blocks/CU
// (was 4), lifting occupancy 29% -> ~58% so ds_read/MFMA/track/barrier
// phases overlap across blocks. E streamed in 32-code chunks (4 KB),
// 3-buffer LDS, 1 barrier/chunk, XOR-swizzled; prefetch after barrier.
__global__ void __launch_bounds__(256, 8) k_argmin_mfma(
        const float* __restrict__ z, const float* __restrict__ e2g,
        const _Float16* __restrict__ ehi,
        int* __restrict__ idxbuf, int* __restrict__ flagcnt,
        int* __restrict__ flaglist) {
    __shared__ __attribute__((aligned(16))) char sE[3][4096];  // 32 codes x 128 B

    int tid = threadIdx.x;
    int wave = tid >> 6, lane = tid & 63;
    int lrow = lane >> 4, lcol = lane & 15;
    int k = blockIdx.y;
    int posbase = blockIdx.x * 64;
    int b = posbase >> 13, s0 = posbase & 8191;
    int wb = wave * 16;

    // ---- X fragment (f16 of z) straight into registers (16 positions/wave)
    const float* zb = z + (((size_t)(b * CCH + k * DIM)) << 13) + s0 + wb;
    f16x8 Xh[2];
#pragma unroll
    for (int kc = 0; kc < 2; ++kc) {
        f16x8 hv;
#pragma unroll
        for (int e = 0; e < 8; ++e) {
            int d = kc * 32 + lrow * 8 + e;
            hv[e] = (_Float16)zb[((size_t)d << 13) + lcol];
        }
        Xh[kc] = hv;
    }

    // ---- E staging: 256 threads x 16 B = one 4 KB chunk (32 codes)
    int r = tid >> 3;                     // code row 0..31
    int q = tid & 7;                      // 16B column 0..7
    const char* bookh = (const char*)(ehi + ((size_t)k << 16));
    const char* src0 = bookh + r * 128 + q * 16;          // + chunk*4096
    int w0 = r * 128 + ((q ^ (r & 7)) << 4);

    const float* e2p = e2g + (k << 10) + lrow * 4;

    // prologue: stage chunk 0 into buffer 0; load chunk-0 e2 vectors
    *(f16x8*)&sE[0][w0] = *(const f16x8*)(src0);
    f32x4 ce2a = *(const f32x4*)(e2p);
    f32x4 ce2b = *(const f32x4*)(e2p + 16);

    float m1f[4], m2f[4];
#pragma unroll
    for (int rr = 0; rr < 4; ++rr) { m1f[rr] = 3.4e38f; m2f[rr] = 3.4e38f; }

    int sxk = (lcol & 7);
    int o0 = ((lrow ^ sxk) << 4);         // K-chunk 0 (dims 0..31)
    int o1 = (((4 + lrow) ^ sxk) << 4);   // K-chunk 1 (dims 32..63)
    int row0 = lcol << 7;                 // st=0 code row byte offset
    int row1 = (16 + lcol) << 7;          // st=1

    int cur = 0, nxt = 1, fre = 2;
    for (int it = 0; it < 32; ++it) {
        __syncthreads();                  // buffer cur ready; vmcnt already 0
        const char* sc = sE[cur];

        f16x8 eh0a = *(const f16x8*)(sc + row0 + o0);
        f16x8 eh1a = *(const f16x8*)(sc + row0 + o1);
        f16x8 eh0b = *(const f16x8*)(sc + row1 + o0);
        f16x8 eh1b = *(const f16x8*)(sc + row1 + o1);

        f16x8 nv0;
        f32x4 ne2a, ne2b;
        bool has = it < 31;
        if (has) {
            nv0 = *(const f16x8*)(src0 + (size_t)(it + 1) * 4096);
            ne2a = *(const f32x4*)(e2p + (it + 1) * 32);
            ne2b = *(const f32x4*)(e2p + (it + 1) * 32 + 16);
        }

#pragma unroll
        for (int st = 0; st < 2; ++st) {
            f16x8 eh0 = st ? eh0b : eh0a;
            f16x8 eh1 = st ? eh1b : eh1a;
            f32x4 e2v = st ? ce2b : ce2a;
            unsigned kit = (unsigned)(it * 2 + st);
            f32x4 acc = e2v;              // score = ||e||^2 - 2x.e (1-term f16)
            acc = __builtin_amdgcn_mfma_f32_16x16x32_f16(eh0, Xh[0], acc, 0, 0, 0);
            acc = __builtin_amdgcn_mfma_f32_16x16x32_f16(eh1, Xh[1], acc, 0, 0, 0);
#pragma unroll
            for (int rr = 0; rr < 4; ++rr) {
                float key = __uint_as_float(
                    (__float_as_uint(acc[rr]) & 0xFFFFFFC0u) | kit);
                m2f[rr] = __builtin_amdgcn_fmed3f(m1f[rr], m2f[rr], key);
                m1f[rr] = fminf(m1f[rr], key);
            }
        }

        if (has) {
            *(f16x8*)&sE[nxt][w0] = nv0;
            ce2a = ne2a; ce2b = ne2b;
        }
        int t = cur; cur = nxt; nxt = fre; fre = t;
    }

    // ---- within-thread merge over r slots (exact, index tie-break)
    float F1, F2; int I1;
    {
        float f1 = 3.4e38f, f2 = 3.4e38f; int i1 = 0;
#pragma unroll
        for (int rr = 0; rr < 4; ++rr) {
            unsigned mb = __float_as_uint(m1f[rr]);
            float f = __uint_as_float(mb & 0xFFFFFFC0u);
            int   c = (int)(mb & 63u) * 16 + lrow * 4 + rr;
            float g = __uint_as_float(__float_as_uint(m2f[rr]) & 0xFFFFFFC0u);
            bool take = (f < f1) || (f == f1 && c < i1);
            float loser = take ? f1 : f;
            f2 = fminf(fminf(f2, g), loser);
            if (take) { f1 = f; i1 = c; }
        }
        F1 = f1; F2 = f2; I1 = i1;
    }

    // ---- merge across lrow groups (4 lanes hold same position)
#pragma unroll
    for (int off = 16; off < 64; off <<= 1) {
        float om1 = __shfl_xor(F1, off);
        float om2 = __shfl_xor(F2, off);
        int   oi  = __shfl_xor(I1, off);
        bool take = (om1 < F1) || (om1 == F1 && oi < I1);
        float loser = take ? F1 : om1;
        F2 = fminf(fminf(F2, om2), loser);
        if (take) { F1 = om1; I1 = oi; }
    }

    // ---- write idx, flag near-ties into per-book list (margin 0.05, proven)
    if (lane < 16) {
        int n = posbase + wb + lane;
        idxbuf[(k << 15) + n] = I1;
        float thr = fmaf(fabsf(F1), 3.2e-5f, 5.0e-2f);
        if (F2 - F1 < thr) {
            int slot = atomicAdd(&flagcnt[k], 1);
            flaglist[(k << 15) + slot] = n;
        }
    }
}

// ---------------------------------------------------------------- rescore v8
// (UNCHANGED — passed round 19, out of top-5.)
// Batched (8 same-book flags per block, one codebook pass) + 2-deep pair
// pipeline; loop-carried state ~130 VGPR.
__global__ void __launch_bounds__(256) k_rescore(
        const float* __restrict__ z, const float* __restrict__ emb,
        const float* __restrict__ e2g, const int* __restrict__ flagcnt,
        const int* __restrict__ flaglist, int* __restrict__ idxbuf) {
    __shared__ __attribute__((aligned(16))) float xsh[8][64];
    __shared__ int meta[8];
    __shared__ float bm[8][256];
    __shared__ int   bx[8][256];
    int tid = threadIdx.x;
    int wave = tid >> 6, lane = tid & 63;
    int k = blockIdx.y;
    int nf = flagcnt[k];
    const f32x4* ek4 = (const f32x4*)(emb + ((size_t)k << 16));
    const float* ee  = e2g + (k << 10);

    for (int base = blockIdx.x * 8; base < nf; base += gridDim.x * 8) {
        __syncthreads();                   // reuse guard
        if (tid < 8) meta[tid] = (base + tid < nf) ? flaglist[(k << 15) + base + tid] : -1;
        __syncthreads();
        for (int j = tid; j < 512; j += 256) {
            int p = j >> 6, d = j & 63;
            int n = meta[p];
            if (n >= 0) {
                int bb = n >> 13, s = n & 8191;
                xsh[p][d] = z[(((size_t)(bb * CCH + k * DIM + d)) << 13) + s];
            }
        }
        __syncthreads();

        const f32x4* ev0 = ek4 + (size_t)(tid) * 16;
        const f32x4* ev1 = ek4 + (size_t)(256 + tid) * 16;
        const f32x4* ev2 = ek4 + (size_t)(512 + tid) * 16;
        const f32x4* ev3 = ek4 + (size_t)(768 + tid) * 16;
        float a0[8], a1[8], a2[8], a3[8];
#pragma unroll
        for (int f = 0; f < 8; ++f) { a0[f] = 0.f; a1[f] = 0.f; a2[f] = 0.f; a3[f] = 0.f; }

        f32x4 A0 = ev0[0], A1 = ev1[0], A2 = ev2[0], A3 = ev3[0];
        f32x4 B0 = ev0[1], B1 = ev1[1], B2 = ev2[1], B3 = ev3[1];
#pragma unroll 1
        for (int jj = 0; jj < 8; ++jj) {
            int j = jj * 2;
            f32x4 C0, C1, C2, C3, D0, D1, D2, D3;
            bool has = jj < 7;
            if (has) {
                C0 = ev0[j + 2]; C1 = ev1[j + 2]; C2 = ev2[j + 2]; C3 = ev3[j + 2];
                D0 = ev0[j + 3]; D1 = ev1[j + 3]; D2 = ev2[j + 3]; D3 = ev3[j + 3];
            }
#pragma unroll
            for (int f = 0; f < 8; ++f) {
                f32x4 xa = *(const f32x4*)&xsh[f][j * 4];       // lane-uniform
                f32x4 xb = *(const f32x4*)&xsh[f][j * 4 + 4];
                a0[f] = fmaf(xa[0], A0[0], a0[f]); a0[f] = fmaf(xa[1], A0[1], a0[f]);
                a0[f] = fmaf(xa[2], A0[2], a0[f]); a0[f] = fmaf(xa[3], A0[3], a0[f]);
                a1[f] = fmaf(xa[0], A1[0], a1[f]); a1[f] = fmaf(xa[1], A1[1], a1[f]);
                a1[f] = fmaf(xa[2], A1[2], a1[f]); a1[f] = fmaf(xa[3], A1[3], a1[f]);
                a2[f] = fmaf(xa[0], A2[0], a2[f]); a2[f] = fmaf(xa[1], A2[1], a2[f]);
                a2[f] = fmaf(xa[2], A2[2], a2[f]); a2[f] = fmaf(xa[3], A2[3], a2[f]);
                a3[f] = fmaf(xa[0], A3[0], a3[f]); a3[f] = fmaf(xa[1], A3[1], a3[f]);
                a3[f] = fmaf(xa[2], A3[2], a3[f]); a3[f] = fmaf(xa[3], A3[3], a3[f]);
                a0[f] = fmaf(xb[0], B0[0], a0[f]); a0[f] = fmaf(xb[1], B0[1], a0[f]);
                a0[f] = fmaf(xb[2], B0[2], a0[f]); a0[f] = fmaf(xb[3], B0[3], a0[f]);
                a1[f] = fmaf(xb[0], B1[0], a1[f]); a1[f] = fmaf(xb[1], B1[1], a1[f]);
                a1[f] = fmaf(xb[2], B1[2], a1[f]); a1[f] = fmaf(xb[3], B1[3], a1[f]);
                a2[f] = fmaf(xb[0], B2[0], a2[f]); a2[f] = fmaf(xb[1], B2[1], a2[f]);
                a2[f] = fmaf(xb[2], B2[2], a2[f]); a2[f] = fmaf(xb[3], B2[3], a2[f]);
                a3[f] = fmaf(xb[0], B3[0], a3[f]); a3[f] = fmaf(xb[1], B3[1], a3[f]);
                a3[f] = fmaf(xb[2], B3[2], a3[f]); a3[f] = fmaf(xb[3], B3[3], a3[f]);
            }
            if (has) {
                A0 = C0; A1 = C1; A2 = C2; A3 = C3;
                B0 = D0; B1 = D1; B2 = D2; B3 = D3;
            }
        }
        float e0 = ee[tid], e1 = ee[256 + tid], e2 = ee[512 + tid], e3 = ee[768 + tid];
#pragma unroll
        for (int f = 0; f < 8; ++f) {
            float best = fmaf(-2.f, a0[f], e0); int bi = tid;
            float d1 = fmaf(-2.f, a1[f], e1);
            float d2 = fmaf(-2.f, a2[f], e2);
            float d3 = fmaf(-2.f, a3[f], e3);
            if (d1 < best) { best = d1; bi = 256 + tid; }
            if (d2 < best) { best = d2; bi = 512 + tid; }
            if (d3 < best) { best = d3; bi = 768 + tid; }
            bm[f][tid] = best;
            bx[f][tid] = bi;
        }
        __syncthreads();

#pragma unroll
        for (int ff = 0; ff < 2; ++ff) {
            int f = wave + ff * 4;
            float bv = bm[f][lane]; int bi = bx[f][lane];
#pragma unroll
            for (int o = 64; o < 256; o += 64) {
                float v2 = bm[f][lane + o]; int x2 = bx[f][lane + o];
                if (v2 < bv || (v2 == bv && x2 < bi)) { bv = v2; bi = x2; }
            }
#pragma unroll
            for (int off = 1; off < 64; off <<= 1) {
                float ob = __shfl_xor(bv, off);
                int   oi = __shfl_xor(bi, off);
                if (ob < bv || (ob == bv && oi < bi)) { bv = ob; bi = oi; }
            }
            if (lane == 0 && meta[f] >= 0) idxbuf[(k << 15) + meta[f]] = bi;
        }
    }
}

// ---------------------------------------------------------------- gather+loss
// 4 consecutive positions per thread -> float4 z loads / q stores.
__global__ void __launch_bounds__(256) k_quant(
        const float* __restrict__ z, const float* __restrict__ emb,
        const int* __restrict__ idxbuf, float* __restrict__ out,
        int* __restrict__ counts, float* __restrict__ partial) {
    int tid = threadIdx.x;
    int q = blockIdx.x * 256 + tid;       // quad index
    int n0 = q * 4;
    int k = blockIdx.y;
    int b = n0 >> 13;
    int s = n0 & 8191;

    int4 bi = *(const int4*)&idxbuf[(k << 15) + n0];
    const f32x4* e0 = (const f32x4*)(emb + ((size_t)k << 16) + ((size_t)bi.x << 6));
    const f32x4* e1 = (const f32x4*)(emb + ((size_t)k << 16) + ((size_t)bi.y << 6));
    const f32x4* e2 = (const f32x4*)(emb + ((size_t)k << 16) + ((size_t)bi.z << 6));
    const f32x4* e3 = (const f32x4*)(emb + ((size_t)k << 16) + ((size_t)bi.w << 6));
    size_t base = (((size_t)(b * CCH + k * DIM)) << 13) + s;

    float sq = 0.f;
#pragma unroll
    for (int j = 0; j < 16; ++j) {
        f32x4 q0 = e0[j], q1 = e1[j], q2 = e2[j], q3 = e3[j];
#pragma unroll
        for (int i = 0; i < 4; ++i) {
            int d = j * 4 + i;
            f32x4 zv = *(const f32x4*)(z + base + ((size_t)d << 13));
            f32x4 ov = {q0[i], q1[i], q2[i], q3[i]};
            *(f32x4*)(out + base + ((size_t)d << 13)) = ov;
            f32x4 df = zv - ov;
            sq = fmaf(df[0], df[0], sq);
            sq = fmaf(df[1], df[1], sq);
            sq = fmaf(df[2], df[2], sq);
            sq = fmaf(df[3], df[3], sq);
        }
    }

    out[ENC_OFF + (size_t)(n0 + 0) * NBOOKS + k] = (float)bi.x;
    out[ENC_OFF + (size_t)(n0 + 1) * NBOOKS + k] = (float)bi.y;
    out[ENC_OFF + (size_t)(n0 + 2) * NBOOKS + k] = (float)bi.z;
    out[ENC_OFF + (size_t)(n0 + 3) * NBOOKS + k] = (float)bi.w;
    atomicAdd(&counts[(k << 10) + bi.x], 1);
    atomicAdd(&counts[(k << 10) + bi.y], 1);
    atomicAdd(&counts[(k << 10) + bi.z], 1);
    atomicAdd(&counts[(k << 10) + bi.w], 1);

    for (int off = 32; off; off >>= 1) sq += __shfl_down(sq, off, 64);
    __shared__ float red[4];
    if ((tid & 63) == 0) red[tid >> 6] = sq;
    __syncthreads();
    if (tid == 0)
        partial[blockIdx.y * gridDim.x + blockIdx.x] = (red[0] + red[1]) + (red[2] + red[3]);
}

// ---------------------------------------------------------------- finalize v2
__global__ void __launch_bounds__(256) k_fin(
        const int* __restrict__ counts, const float* __restrict__ partial,
        float* __restrict__ out) {
    __shared__ float shl[4];
    __shared__ float shp[4];
    int tid = threadIdx.x;
    int wave = tid >> 6, lane = tid & 63;

    // loss: 128 partials (32 blocks x 4 books)
    float s = tid < 128 ? partial[tid] : 0.f;
    for (int off = 32; off; off >>= 1) s += __shfl_down(s, off, 64);
    if (lane == 0) shl[wave] = s;

    // perplexity: wave w handles book w, lane handles 16 codes
    float h = 0.f;
    const int* ck = counts + (wave << 10) + lane * 16;
#pragma unroll
    for (int j = 0; j < 16; ++j) {
        float p = (float)ck[j] * (1.f / 32768.f);
        h += p * logf(p + 1e-10f);
    }
    for (int off = 32; off; off >>= 1) h += __shfl_down(h, off, 64);
    if (lane == 0) shp[wave] = expf(-h);
    __syncthreads();
    if (tid == 0) {
        out[LOSS_OFF] = 0.25f * ((shl[0] + shl[1]) + (shl[2] + shl[3])) / 8388608.f;
        out[PERP_OFF] = 0.25f * ((shp[0] + shp[1]) + (shp[2] + shp[3]));
    }
}

// ----------------------------------------------------------------
extern "C" void kernel_launch(void* const* d_in, const int* in_sizes, int n_in,
                              void* d_out, int out_size, void* d_ws, size_t ws_size,
                              hipStream_t stream) {
    const float* z   = (const float*)d_in[0];
    const float* emb = (const float*)d_in[1];
    float* out = (float*)d_out;
    char* ws = (char*)d_ws;

    float*    e2       = (float*)(ws + WS_E2);
    _Float16* ehi      = (_Float16*)(ws + WS_EHI);
    int*      idxbuf   = (int*)(ws + WS_IDX);
    int*      counts   = (int*)(ws + WS_CNT);
    float*    partial  = (float*)(ws + WS_PART);
    int*      flagcnt  = (int*)(ws + WS_FLAGCNT);
    int*      flaglist = (int*)(ws + WS_FLAGS);

    k_eprep2<<<16, 256, 0, stream>>>(emb, e2, ehi, counts, flagcnt);

    dim3 agrid(NPOS / 64, NBOOKS);
    k_argmin_mfma<<<agrid, 256, 0, stream>>>(z, e2, ehi, idxbuf, flagcnt, flaglist);

    dim3 rgrid(256, NBOOKS);
    k_rescore<<<rgrid, 256, 0, stream>>>(z, emb, e2, flagcnt, flaglist, idxbuf);

    dim3 qgrid(NPOS / 1024, NBOOKS);
    k_quant<<<qgrid, 256, 0, stream>>>(z, emb, idxbuf, out, counts, partial);
    k_fin<<<1, 256, 0, stream>>>(counts, partial, out);
}

// Round 21
// 105.175 us; speedup vs baseline: 1.2197x; 1.0196x over previous
//
#include <hip/hip_runtime.h>

// Problem constants
#define NBOOKS 4
#define CODES  1024
#define DIM    64
#define NPOS   32768          // B*T*H*W
#define CCH    256            // NB*DIM (channel dim of z)
#define ENC_OFF  8388608
#define LOSS_OFF 8519680
#define PERP_OFF 8519681

// workspace byte offsets
#define WS_E2      0              // 4096 f32 (raw ||e||^2)
#define WS_EHI     16384          // 4096*64 f16 = 512 KB  (f16 of -2*e)
#define WS_IDX     1064960        // 131072 int
#define WS_CNT     1589248        // 4096 int
#define WS_PART    1605632        // 128 f32
#define WS_FLAGCNT 1607680        // 4 ints (per-book flag counts)
#define WS_FLAGS   1607696        // 4 x 32768 ints (per-book flag lists)

typedef _Float16 f16x8 __attribute__((ext_vector_type(8)));
typedef _Float16 f16x4 __attribute__((ext_vector_type(4)));
typedef float    f32x4 __attribute__((ext_vector_type(4)));

// ------------------------------------------- prep: e2, f16(-2e), zeroing
__global__ void k_eprep2(const float* __restrict__ emb, float* __restrict__ e2,
                         _Float16* __restrict__ ehi,
                         int* __restrict__ counts, int* __restrict__ flagcnt) {
    int i = blockIdx.x * 256 + threadIdx.x;            // row 0..4095 = k*1024+c
    counts[i] = 0;
    if (i < 4) flagcnt[i] = 0;
    const float4* e = (const float4*)(emb + ((size_t)i << 6));
    _Float16* hp = ehi + ((size_t)i << 6);
    float s = 0.f;
#pragma unroll
    for (int j = 0; j < 16; ++j) {
        float4 v = e[j];
        s += v.x * v.x + v.y * v.y + v.z * v.z + v.w * v.w;
        f16x4 hv;
        hv[0] = (_Float16)(-2.f * v.x);
        hv[1] = (_Float16)(-2.f * v.y);
        hv[2] = (_Float16)(-2.f * v.z);
        hv[3] = (_Float16)(-2.f * v.w);
        *(f16x4*)&hp[j * 4] = hv;
    }
    e2[i] = s;           // raw ||e||^2; score = e2 - 2x.e (sign handled in float domain)
}

// ---------------------------------------------------------------- MFMA argmin v13
// Same numerics as proven v10/v12 (1-term f16, margin 0.05, per-book flags).
// Block = 64 positions, 8 blocks/CU. Chunks doubled to 64 codes (8 KB),
// 2-buffer LDS (16 KB): barrier count 32 -> 16, per-chunk addressing and
// loop overhead halved. Staging 32B/thread, XOR swizzle; read row =
// st*16+lcol keeps (row&7) == (lcol&7) so read addressing is unchanged.
__global__ void __launch_bounds__(256, 8) k_argmin_mfma(
        const float* __restrict__ z, const float* __restrict__ e2g,
        const _Float16* __restrict__ ehi,
        int* __restrict__ idxbuf, int* __restrict__ flagcnt,
        int* __restrict__ flaglist) {
    __shared__ __attribute__((aligned(16))) char sE[2][8192];  // 64 codes x 128 B

    int tid = threadIdx.x;
    int wave = tid >> 6, lane = tid & 63;
    int lrow = lane >> 4, lcol = lane & 15;
    int k = blockIdx.y;
    int posbase = blockIdx.x * 64;
    int b = posbase >> 13, s0 = posbase & 8191;
    int wb = wave * 16;

    // ---- X fragment (f16 of z) straight into registers (16 positions/wave)
    const float* zb = z + (((size_t)(b * CCH + k * DIM)) << 13) + s0 + wb;
    f16x8 Xh[2];
#pragma unroll
    for (int kc = 0; kc < 2; ++kc) {
        f16x8 hv;
#pragma unroll
        for (int e = 0; e < 8; ++e) {
            int d = kc * 32 + lrow * 8 + e;
            hv[e] = (_Float16)zb[((size_t)d << 13) + lcol];
        }
        Xh[kc] = hv;
    }

    // ---- E staging: 256 threads x 32 B = one 8 KB chunk (64 codes)
    int r = tid >> 2;                     // code row 0..63
    int q = tid & 3;                      // 32B quarter 0..3
    const char* bookh = (const char*)(ehi + ((size_t)k << 16));
    const char* src0 = bookh + r * 128 + q * 32;          // + chunk*8192
    int c0 = 2 * q, c1 = 2 * q + 1;
    int w0 = r * 128 + ((c0 ^ (r & 7)) << 4);
    int w1 = r * 128 + ((c1 ^ (r & 7)) << 4);

    const float* e2p = e2g + (k << 10) + lrow * 4;

    // prologue: stage chunk 0 into buffer 0; load chunk-0 e2 vectors
    {
        f16x8 v0 = *(const f16x8*)(src0);
        f16x8 v1 = *(const f16x8*)(src0 + 16);
        *(f16x8*)&sE[0][w0] = v0;
        *(f16x8*)&sE[0][w1] = v1;
    }
    f32x4 ce2[4];
#pragma unroll
    for (int st = 0; st < 4; ++st) ce2[st] = *(const f32x4*)(e2p + st * 16);

    float m1f[4], m2f[4];
#pragma unroll
    for (int rr = 0; rr < 4; ++rr) { m1f[rr] = 3.4e38f; m2f[rr] = 3.4e38f; }

    int sxk = (lcol & 7);
    int o0 = ((lrow ^ sxk) << 4);         // K-chunk 0 (dims 0..31)
    int o1 = (((4 + lrow) ^ sxk) << 4);   // K-chunk 1 (dims 32..63)

    int cur = 0;
    for (int it = 0; it < 16; ++it) {
        __syncthreads();                  // buffer cur ready (own lgkm drained)
        const char* sc = sE[cur];

        // ---- ds_read all current-chunk fragments (4 st halves)
        f16x8 ehA[4], ehB[4];
#pragma unroll
        for (int st = 0; st < 4; ++st) {
            int rowb = (st * 16 + lcol) << 7;
            ehA[st] = *(const f16x8*)(sc + rowb + o0);
            ehB[st] = *(const f16x8*)(sc + rowb + o1);
        }

        // ---- issue next-chunk global prefetch (lands during MFMAs)
        f16x8 nv0, nv1;
        f32x4 ne2[4];
        bool has = it < 15;
        if (has) {
            const char* sp = src0 + (size_t)(it + 1) * 8192;
            nv0 = *(const f16x8*)(sp);
            nv1 = *(const f16x8*)(sp + 16);
#pragma unroll
            for (int st = 0; st < 4; ++st)
                ne2[st] = *(const f32x4*)(e2p + (it + 1) * 64 + st * 16);
        }

        // ---- MFMA + tracking
#pragma unroll
        for (int st = 0; st < 4; ++st) {
            unsigned kit = (unsigned)(it * 4 + st);
            f32x4 acc = ce2[st];          // score = ||e||^2 - 2x.e (1-term f16)
            acc = __builtin_amdgcn_mfma_f32_16x16x32_f16(ehA[st], Xh[0], acc, 0, 0, 0);
            acc = __builtin_amdgcn_mfma_f32_16x16x32_f16(ehB[st], Xh[1], acc, 0, 0, 0);
#pragma unroll
            for (int rr = 0; rr < 4; ++rr) {
                float key = __uint_as_float(
                    (__float_as_uint(acc[rr]) & 0xFFFFFFC0u) | kit);
                m2f[rr] = __builtin_amdgcn_fmed3f(m1f[rr], m2f[rr], key);
                m1f[rr] = fminf(m1f[rr], key);
            }
        }

        // ---- write next chunk to the other buffer (vmcnt wait lands here)
        if (has) {
            *(f16x8*)&sE[cur ^ 1][w0] = nv0;
            *(f16x8*)&sE[cur ^ 1][w1] = nv1;
#pragma unroll
            for (int st = 0; st < 4; ++st) ce2[st] = ne2[st];
        }
        cur ^= 1;
    }

    // ---- within-thread merge over r slots (exact, index tie-break)
    float F1, F2; int I1;
    {
        float f1 = 3.4e38f, f2 = 3.4e38f; int i1 = 0;
#pragma unroll
        for (int rr = 0; rr < 4; ++rr) {
            unsigned mb = __float_as_uint(m1f[rr]);
            float f = __uint_as_float(mb & 0xFFFFFFC0u);
            int   c = (int)(mb & 63u) * 16 + lrow * 4 + rr;
            float g = __uint_as_float(__float_as_uint(m2f[rr]) & 0xFFFFFFC0u);
            bool take = (f < f1) || (f == f1 && c < i1);
            float loser = take ? f1 : f;
            f2 = fminf(fminf(f2, g), loser);
            if (take) { f1 = f; i1 = c; }
        }
        F1 = f1; F2 = f2; I1 = i1;
    }

    // ---- merge across lrow groups (4 lanes hold same position)
#pragma unroll
    for (int off = 16; off < 64; off <<= 1) {
        float om1 = __shfl_xor(F1, off);
        float om2 = __shfl_xor(F2, off);
        int   oi  = __shfl_xor(I1, off);
        bool take = (om1 < F1) || (om1 == F1 && oi < I1);
        float loser = take ? F1 : om1;
        F2 = fminf(fminf(F2, om2), loser);
        if (take) { F1 = om1; I1 = oi; }
    }

    // ---- write idx, flag near-ties into per-book list (margin 0.05, proven)
    if (lane < 16) {
        int n = posbase + wb + lane;
        idxbuf[(k << 15) + n] = I1;
        float thr = fmaf(fabsf(F1), 3.2e-5f, 5.0e-2f);
        if (F2 - F1 < thr) {
            int slot = atomicAdd(&flagcnt[k], 1);
            flaglist[(k << 15) + slot] = n;
        }
    }
}

// ---------------------------------------------------------------- rescore v8
// (UNCHANGED — proven rounds 19/20.) Batched (8 same-book flags per block,
// one codebook pass) + 2-deep pair pipeline; ~130 VGPR loop-carried state.
__global__ void __launch_bounds__(256) k_rescore(
        const float* __restrict__ z, const float* __restrict__ emb,
        const float* __restrict__ e2g, const int* __restrict__ flagcnt,
        const int* __restrict__ flaglist, int* __restrict__ idxbuf) {
    __shared__ __attribute__((aligned(16))) float xsh[8][64];
    __shared__ int meta[8];
    __shared__ float bm[8][256];
    __shared__ int   bx[8][256];
    int tid = threadIdx.x;
    int wave = tid >> 6, lane = tid & 63;
    int k = blockIdx.y;
    int nf = flagcnt[k];
    const f32x4* ek4 = (const f32x4*)(emb + ((size_t)k << 16));
    const float* ee  = e2g + (k << 10);

    for (int base = blockIdx.x * 8; base < nf; base += gridDim.x * 8) {
        __syncthreads();                   // reuse guard
        if (tid < 8) meta[tid] = (base + tid < nf) ? flaglist[(k << 15) + base + tid] : -1;
        __syncthreads();
        for (int j = tid; j < 512; j += 256) {
            int p = j >> 6, d = j & 63;
            int n = meta[p];
            if (n >= 0) {
                int bb = n >> 13, s = n & 8191;
                xsh[p][d] = z[(((size_t)(bb * CCH + k * DIM + d)) << 13) + s];
            }
        }
        __syncthreads();

        const f32x4* ev0 = ek4 + (size_t)(tid) * 16;
        const f32x4* ev1 = ek4 + (size_t)(256 + tid) * 16;
        const f32x4* ev2 = ek4 + (size_t)(512 + tid) * 16;
        const f32x4* ev3 = ek4 + (size_t)(768 + tid) * 16;
        float a0[8], a1[8], a2[8], a3[8];
#pragma unroll
        for (int f = 0; f < 8; ++f) { a0[f] = 0.f; a1[f] = 0.f; a2[f] = 0.f; a3[f] = 0.f; }

        f32x4 A0 = ev0[0], A1 = ev1[0], A2 = ev2[0], A3 = ev3[0];
        f32x4 B0 = ev0[1], B1 = ev1[1], B2 = ev2[1], B3 = ev3[1];
#pragma unroll 1
        for (int jj = 0; jj < 8; ++jj) {
            int j = jj * 2;
            f32x4 C0, C1, C2, C3, D0, D1, D2, D3;
            bool has = jj < 7;
            if (has) {
                C0 = ev0[j + 2]; C1 = ev1[j + 2]; C2 = ev2[j + 2]; C3 = ev3[j + 2];
                D0 = ev0[j + 3]; D1 = ev1[j + 3]; D2 = ev2[j + 3]; D3 = ev3[j + 3];
            }
#pragma unroll
            for (int f = 0; f < 8; ++f) {
                f32x4 xa = *(const f32x4*)&xsh[f][j * 4];       // lane-uniform
                f32x4 xb = *(const f32x4*)&xsh[f][j * 4 + 4];
                a0[f] = fmaf(xa[0], A0[0], a0[f]); a0[f] = fmaf(xa[1], A0[1], a0[f]);
                a0[f] = fmaf(xa[2], A0[2], a0[f]); a0[f] = fmaf(xa[3], A0[3], a0[f]);
                a1[f] = fmaf(xa[0], A1[0], a1[f]); a1[f] = fmaf(xa[1], A1[1], a1[f]);
                a1[f] = fmaf(xa[2], A1[2], a1[f]); a1[f] = fmaf(xa[3], A1[3], a1[f]);
                a2[f] = fmaf(xa[0], A2[0], a2[f]); a2[f] = fmaf(xa[1], A2[1], a2[f]);
                a2[f] = fmaf(xa[2], A2[2], a2[f]); a2[f] = fmaf(xa[3], A2[3], a2[f]);
                a3[f] = fmaf(xa[0], A3[0], a3[f]); a3[f] = fmaf(xa[1], A3[1], a3[f]);
                a3[f] = fmaf(xa[2], A3[2], a3[f]); a3[f] = fmaf(xa[3], A3[3], a3[f]);
                a0[f] = fmaf(xb[0], B0[0], a0[f]); a0[f] = fmaf(xb[1], B0[1], a0[f]);
                a0[f] = fmaf(xb[2], B0[2], a0[f]); a0[f] = fmaf(xb[3], B0[3], a0[f]);
                a1[f] = fmaf(xb[0], B1[0], a1[f]); a1[f] = fmaf(xb[1], B1[1], a1[f]);
                a1[f] = fmaf(xb[2], B1[2], a1[f]); a1[f] = fmaf(xb[3], B1[3], a1[f]);
                a2[f] = fmaf(xb[0], B2[0], a2[f]); a2[f] = fmaf(xb[1], B2[1], a2[f]);
                a2[f] = fmaf(xb[2], B2[2], a2[f]); a2[f] = fmaf(xb[3], B2[3], a2[f]);
                a3[f] = fmaf(xb[0], B3[0], a3[f]); a3[f] = fmaf(xb[1], B3[1], a3[f]);
                a3[f] = fmaf(xb[2], B3[2], a3[f]); a3[f] = fmaf(xb[3], B3[3], a3[f]);
            }
            if (has) {
                A0 = C0; A1 = C1; A2 = C2; A3 = C3;
                B0 = D0; B1 = D1; B2 = D2; B3 = D3;
            }
        }
        float e0 = ee[tid], e1 = ee[256 + tid], e2 = ee[512 + tid], e3 = ee[768 + tid];
#pragma unroll
        for (int f = 0; f < 8; ++f) {
            float best = fmaf(-2.f, a0[f], e0); int bi = tid;
            float d1 = fmaf(-2.f, a1[f], e1);
            float d2 = fmaf(-2.f, a2[f], e2);
            float d3 = fmaf(-2.f, a3[f], e3);
            if (d1 < best) { best = d1; bi = 256 + tid; }
            if (d2 < best) { best = d2; bi = 512 + tid; }
            if (d3 < best) { best = d3; bi = 768 + tid; }
            bm[f][tid] = best;
            bx[f][tid] = bi;
        }
        __syncthreads();

#pragma unroll
        for (int ff = 0; ff < 2; ++ff) {
            int f = wave + ff * 4;
            float bv = bm[f][lane]; int bi = bx[f][lane];
#pragma unroll
            for (int o = 64; o < 256; o += 64) {
                float v2 = bm[f][lane + o]; int x2 = bx[f][lane + o];
                if (v2 < bv || (v2 == bv && x2 < bi)) { bv = v2; bi = x2; }
            }
#pragma unroll
            for (int off = 1; off < 64; off <<= 1) {
                float ob = __shfl_xor(bv, off);
                int   oi = __shfl_xor(bi, off);
                if (ob < bv || (ob == bv && oi < bi)) { bv = ob; bi = oi; }
            }
            if (lane == 0 && meta[f] >= 0) idxbuf[(k << 15) + meta[f]] = bi;
        }
    }
}

// ---------------------------------------------------------------- gather+loss
// 4 consecutive positions per thread -> float4 z loads / q stores.
__global__ void __launch_bounds__(256) k_quant(
        const float* __restrict__ z, const float* __restrict__ emb,
        const int* __restrict__ idxbuf, float* __restrict__ out,
        int* __restrict__ counts, float* __restrict__ partial) {
    int tid = threadIdx.x;
    int q = blockIdx.x * 256 + tid;       // quad index
    int n0 = q * 4;
    int k = blockIdx.y;
    int b = n0 >> 13;
    int s = n0 & 8191;

    int4 bi = *(const int4*)&idxbuf[(k << 15) + n0];
    const f32x4* e0 = (const f32x4*)(emb + ((size_t)k << 16) + ((size_t)bi.x << 6));
    const f32x4* e1 = (const f32x4*)(emb + ((size_t)k << 16) + ((size_t)bi.y << 6));
    const f32x4* e2 = (const f32x4*)(emb + ((size_t)k << 16) + ((size_t)bi.z << 6));
    const f32x4* e3 = (const f32x4*)(emb + ((size_t)k << 16) + ((size_t)bi.w << 6));
    size_t base = (((size_t)(b * CCH + k * DIM)) << 13) + s;

    float sq = 0.f;
#pragma unroll
    for (int j = 0; j < 16; ++j) {
        f32x4 q0 = e0[j], q1 = e1[j], q2 = e2[j], q3 = e3[j];
#pragma unroll
        for (int i = 0; i < 4; ++i) {
            int d = j * 4 + i;
            f32x4 zv = *(const f32x4*)(z + base + ((size_t)d << 13));
            f32x4 ov = {q0[i], q1[i], q2[i], q3[i]};
            *(f32x4*)(out + base + ((size_t)d << 13)) = ov;
            f32x4 df = zv - ov;
            sq = fmaf(df[0], df[0], sq);
            sq = fmaf(df[1], df[1], sq);
            sq = fmaf(df[2], df[2], sq);
            sq = fmaf(df[3], df[3], sq);
        }
    }

    out[ENC_OFF + (size_t)(n0 + 0) * NBOOKS + k] = (float)bi.x;
    out[ENC_OFF + (size_t)(n0 + 1) * NBOOKS + k] = (float)bi.y;
    out[ENC_OFF + (size_t)(n0 + 2) * NBOOKS + k] = (float)bi.z;
    out[ENC_OFF + (size_t)(n0 + 3) * NBOOKS + k] = (float)bi.w;
    atomicAdd(&counts[(k << 10) + bi.x], 1);
    atomicAdd(&counts[(k << 10) + bi.y], 1);
    atomicAdd(&counts[(k << 10) + bi.z], 1);
    atomicAdd(&counts[(k << 10) + bi.w], 1);

    for (int off = 32; off; off >>= 1) sq += __shfl_down(sq, off, 64);
    __shared__ float red[4];
    if ((tid & 63) == 0) red[tid >> 6] = sq;
    __syncthreads();
    if (tid == 0)
        partial[blockIdx.y * gridDim.x + blockIdx.x] = (red[0] + red[1]) + (red[2] + red[3]);
}

// ---------------------------------------------------------------- finalize v2
__global__ void __launch_bounds__(256) k_fin(
        const int* __restrict__ counts, const float* __restrict__ partial,
        float* __restrict__ out) {
    __shared__ float shl[4];
    __shared__ float shp[4];
    int tid = threadIdx.x;
    int wave = tid >> 6, lane = tid & 63;

    // loss: 128 partials (32 blocks x 4 books)
    float s = tid < 128 ? partial[tid] : 0.f;
    for (int off = 32; off; off >>= 1) s += __shfl_down(s, off, 64);
    if (lane == 0) shl[wave] = s;

    // perplexity: wave w handles book w, lane handles 16 codes
    float h = 0.f;
    const int* ck = counts + (wave << 10) + lane * 16;
#pragma unroll
    for (int j = 0; j < 16; ++j) {
        float p = (float)ck[j] * (1.f / 32768.f);
        h += p * logf(p + 1e-10f);
    }
    for (int off = 32; off; off >>= 1) h += __shfl_down(h, off, 64);
    if (lane == 0) shp[wave] = expf(-h);
    __syncthreads();
    if (tid == 0) {
        out[LOSS_OFF] = 0.25f * ((shl[0] + shl[1]) + (shl[2] + shl[3])) / 8388608.f;
        out[PERP_OFF] = 0.25f * ((shp[0] + shp[1]) + (shp[2] + shp[3]));
    }
}

// ----------------------------------------------------------------
extern "C" void kernel_launch(void* const* d_in, const int* in_sizes, int n_in,
                              void* d_out, int out_size, void* d_ws, size_t ws_size,
                              hipStream_t stream) {
    const float* z   = (const float*)d_in[0];
    const float* emb = (const float*)d_in[1];
    float* out = (float*)d_out;
    char* ws = (char*)d_ws;

    float*    e2       = (float*)(ws + WS_E2);
    _Float16* ehi      = (_Float16*)(ws + WS_EHI);
    int*      idxbuf   = (int*)(ws + WS_IDX);
    int*      counts   = (int*)(ws + WS_CNT);
    float*    partial  = (float*)(ws + WS_PART);
    int*      flagcnt  = (int*)(ws + WS_FLAGCNT);
    int*      flaglist = (int*)(ws + WS_FLAGS);

    k_eprep2<<<16, 256, 0, stream>>>(emb, e2, ehi, counts, flagcnt);

    dim3 agrid(NPOS / 64, NBOOKS);
    k_argmin_mfma<<<agrid, 256, 0, stream>>>(z, e2, ehi, idxbuf, flagcnt, flaglist);

    dim3 rgrid(256, NBOOKS);
    k_rescore<<<rgrid, 256, 0, stream>>>(z, emb, e2, flagcnt, flaglist, idxbuf);

    dim3 qgrid(NPOS / 1024, NBOOKS);
    k_quant<<<qgrid, 256, 0, stream>>>(z, emb, idxbuf, out, counts, partial);
    k_fin<<<1, 256, 0, stream>>>(counts, partial, out);
}